// Round 7
// baseline (649.114 us; speedup 1.0000x reference)
//
#include <hip/hip_runtime.h>
#include <hip/hip_fp16.h>

// GCN link-prediction forward. CSR aggregation with XCD-sliced, slice-major
// gather tables (per-XCD L2-resident), wide converged gather loads; fp16
// storage; fp16 MFMA GEMMs; sliced decode with fp32 partial sums.
// Inputs: x[N,256] f32, train_edges[2,E] i32, pos[2,E] i32, neg[2,E] i32,
//         W1[256,256], b1[256], W2[256,128], b2[128]  (all f32)
// Output: logits[2E] f32.

#define NFEAT 256
#define HID   256
#define OUTF  128
#define SCAN_T 1024

typedef _Float16 f16x8 __attribute__((ext_vector_type(8)));
typedef float    f32x4 __attribute__((ext_vector_type(4)));

// ---------------- degree ----------------
__global__ void k_init_deg(float* __restrict__ deg, int n) {
    int i = blockIdx.x * blockDim.x + threadIdx.x;
    if (i < n) deg[i] = 1.0f;   // self-loop
}

__global__ void k_count_deg(const int* __restrict__ ei, float* __restrict__ deg, int E) {
    int e = blockIdx.x * blockDim.x + threadIdx.x;
    if (e < E) atomicAdd(&deg[ei[E + e]], 1.0f);   // dst row
}

// ---------------- scan: rowptr/cursor from deg, dinv in place ----------------
__global__ __launch_bounds__(SCAN_T) void k_scan(
        float* __restrict__ deg_dinv, int* __restrict__ rowptr,
        int* __restrict__ cursor, int n) {
    __shared__ int swsum[16];
    __shared__ int s_total;
    __shared__ int s_chunk;
    const int t    = threadIdx.x;
    const int wave = t >> 6;
    const int lane = t & 63;
    if (t == 0) s_total = 0;

    for (int base = 0; base < n; base += SCAN_T) {
        int i = base + t;
        float dg = 1.0f;
        int v = 0;
        if (i < n) { dg = deg_dinv[i]; v = (int)dg - 1; }  // edge count (no self)
        int sc = v;
#pragma unroll
        for (int off = 1; off < 64; off <<= 1) {
            int y = __shfl_up(sc, off);
            if (lane >= off) sc += y;
        }
        if (lane == 63) swsum[wave] = sc;
        __syncthreads();
        if (t < 16) {
            int w = swsum[t];
            int scw = w;
#pragma unroll
            for (int off = 1; off < 16; off <<= 1) {
                int y = __shfl_up(scw, off);
                if (t >= off) scw += y;
            }
            swsum[t] = scw - w;
            if (t == 15) s_chunk = scw;
        }
        __syncthreads();
        int rp = s_total + swsum[wave] + (sc - v);
        if (i < n) {
            rowptr[i] = rp;
            cursor[i] = rp;
            deg_dinv[i] = rsqrtf(dg);
        }
        __syncthreads();
        if (t == 0) s_total += s_chunk;
        __syncthreads();
    }
    if (t == 0) rowptr[n] = s_total;
}

// ---------------- fill CSR adjacency (src ids grouped by dst) ----------------
__global__ void k_fill(const int* __restrict__ ei, int* __restrict__ cursor,
                       int* __restrict__ eidx, int E) {
    int e = blockIdx.x * blockDim.x + threadIdx.x;
    if (e < E) {
        int s = ei[e];
        int d = ei[E + e];
        int p = atomicAdd(&cursor[d], 1);
        eidx[p] = s;
    }
}

// ---------------- W transpose+convert: Wt[m][k] = (half)W[k][m] ----------------
__global__ __launch_bounds__(256) void k_wt(const float* __restrict__ W,
                                            __half* __restrict__ Wt, int K, int M) {
    __shared__ float tile[32][33];
    int k0 = blockIdx.x * 32, m0 = blockIdx.y * 32;
    int tx = threadIdx.x & 31, ty = threadIdx.x >> 5;  // ty 0..7
#pragma unroll
    for (int r = 0; r < 4; ++r)
        tile[ty + r * 8][tx] = W[(size_t)(k0 + ty + r * 8) * M + m0 + tx];
    __syncthreads();
#pragma unroll
    for (int r = 0; r < 4; ++r)
        Wt[(size_t)(m0 + ty + r * 8) * K + k0 + tx] = __float2half(tile[tx][ty + r * 8]);
}

// ---------------- MFMA GEMM: out = (half)(dinv[r] * A @ Wt^T) ----------------
// Block: 256 threads = 4 waves (2x2). Block tile (2*MT*16) x 128, wave (MT*16) x 64.
// A: [n][K] (f32 if AF32 else f16). Wt: [M][K] f16. K % 32 == 0.
// Output is SLICE-MAJOR: out[(col>>SWL)][row][col & (SW-1)], SW = 1<<SWL feats/slice.
template <int MT, bool AF32, int SWL>
__global__ __launch_bounds__(256) void k_gemm_mfma(
        const void* __restrict__ Aptr, const __half* __restrict__ Wt,
        const float* __restrict__ dinv, __half* __restrict__ outp,
        int n, int K, int M) {
    constexpr int BM = 2 * MT * 16;
    __shared__ __half As[BM][40];      // [row][k], +8 pad: 2-way banks (free)
    __shared__ __half Bs[128][40];     // [col][k]
    __shared__ __half Cs[4][16][72];   // per-wave C repack (16B-aligned rows)

    const int t    = threadIdx.x;
    const int wave = t >> 6;
    const int lane = t & 63;
    const int row0 = blockIdx.x * BM;
    const int col0 = blockIdx.y * 128;
    const int wm = wave >> 1, wn = wave & 1;
    const int lr = lane & 15;          // fragment m/n index
    const int kq = lane >> 4;          // k-quad: k = kq*8 + j

    f32x4 acc[MT][4];
#pragma unroll
    for (int i = 0; i < MT; ++i)
#pragma unroll
        for (int j = 0; j < 4; ++j) acc[i][j] = (f32x4){0.f, 0.f, 0.f, 0.f};

    for (int k0 = 0; k0 < K; k0 += 32) {
        // ---- stage A tile: BM rows x 32 k ----
        if (AF32) {
            const float* A = (const float*)Aptr;
#pragma unroll
            for (int it = 0; it < BM * 8 / 256; ++it) {
                int q = t + it * 256;
                int r = q >> 3, c4 = q & 7;       // c4: which 4-float chunk
                int gr = min(row0 + r, n - 1);
                float4 v = *(const float4*)&A[(size_t)gr * K + k0 + c4 * 4];
                __half2* dst = (__half2*)&As[r][c4 * 4];
                dst[0] = __floats2half2_rn(v.x, v.y);
                dst[1] = __floats2half2_rn(v.z, v.w);
            }
        } else {
            const __half* A = (const __half*)Aptr;
#pragma unroll
            for (int it = 0; it < BM * 4 / 256; ++it) {
                int q = t + it * 256;
                int r = q >> 2, c8 = q & 3;       // c8: which 8-half chunk
                int gr = min(row0 + r, n - 1);
                *(float4*)&As[r][c8 * 8] = *(const float4*)&A[(size_t)gr * K + k0 + c8 * 8];
            }
        }
        // ---- stage B tile: 128 cols x 32 k from Wt ----
#pragma unroll
        for (int it = 0; it < 2; ++it) {
            int q = t + it * 256;
            int r = q >> 2, c8 = q & 3;
            *(float4*)&Bs[r][c8 * 8] = *(const float4*)&Wt[(size_t)(col0 + r) * K + k0 + c8 * 8];
        }
        __syncthreads();

        f16x8 b[4];
#pragma unroll
        for (int j = 0; j < 4; ++j)
            b[j] = *(const f16x8*)&Bs[wn * 64 + j * 16 + lr][kq * 8];
#pragma unroll
        for (int i = 0; i < MT; ++i) {
            f16x8 a = *(const f16x8*)&As[wm * MT * 16 + i * 16 + lr][kq * 8];
#pragma unroll
            for (int j = 0; j < 4; ++j)
                acc[i][j] = __builtin_amdgcn_mfma_f32_16x16x32_f16(a, b[j], acc[i][j], 0, 0, 0);
        }
        __syncthreads();
    }

    // ---- epilogue: scale by dinv, f16 convert, repack via LDS, slice-major stores ----
    constexpr int SW = 1 << SWL;
#pragma unroll
    for (int i = 0; i < MT; ++i) {
        int gr0 = row0 + wm * MT * 16 + i * 16;
        float dv[4];
#pragma unroll
        for (int r = 0; r < 4; ++r)
            dv[r] = dinv[min(gr0 + kq * 4 + r, n - 1)];
        __syncthreads();   // protect Cs reuse across i iterations
#pragma unroll
        for (int j = 0; j < 4; ++j)
#pragma unroll
            for (int r = 0; r < 4; ++r)
                Cs[wave][kq * 4 + r][j * 16 + lr] = __float2half(acc[i][j][r] * dv[r]);
        __syncthreads();
        int r1 = lane >> 3, c1 = (lane & 7) * 8;
#pragma unroll
        for (int h = 0; h < 2; ++h) {
            int grow = gr0 + r1 + h * 8;
            if (grow < n) {
                int col = col0 + wn * 64 + c1;    // multiple of 8; 8 halves stay in-slice
                size_t oidx = ((size_t)(col >> SWL) * n + grow) * SW + (col & (SW - 1));
                *(float4*)&outp[oidx] = *(const float4*)&Cs[wave][r1 + h * 8][c1];
            }
        }
    }
}

// ---------------- layer-1 aggregate: g1s [8][n][32] f16, wave per (node,slice) ----
// 8 edges x 8 lanes x 8B per iteration; eidx software-prefetched.
__global__ __launch_bounds__(256) void k_agg1(
        const int* __restrict__ rowptr, const int* __restrict__ eidx,
        const __half* __restrict__ g1s, const float* __restrict__ dinv,
        const float* __restrict__ bias, __half* __restrict__ out, int n) {
    const int slice = blockIdx.x & 7;
    const int node  = (blockIdx.x >> 3) * 4 + (threadIdx.x >> 6);
    const int lane  = threadIdx.x & 63;
    const int sub   = lane >> 3;      // edge slot 0..7
    const int fl    = lane & 7;       // feats fl*4 .. fl*4+3
    if (node >= n) return;
    const int j0   = rowptr[node];
    const int end  = rowptr[node + 1];
    const int last = max(end - 1, 0);
    const __half* base = g1s + (size_t)slice * n * 32;

    union HF { float2 f; __half2 h[2]; };
    float4 acc = make_float4(0.f, 0.f, 0.f, 0.f);
    {   // self term, counted once
        HF u; u.f = *(const float2*)&base[(size_t)node * 32 + fl * 4];
        if (sub == 0) {
            float2 lo = __half22float2(u.h[0]), hi = __half22float2(u.h[1]);
            acc = make_float4(lo.x, lo.y, hi.x, hi.y);
        }
    }
    int row = eidx[min(j0 + sub, last)];
    for (int j = j0; j < end; j += 8) {
        int nrow = eidx[min(j + 8 + sub, last)];   // prefetch next chunk's index
        HF u; u.f = *(const float2*)&base[(size_t)row * 32 + fl * 4];
        if (j + sub < end) {
            float2 lo = __half22float2(u.h[0]), hi = __half22float2(u.h[1]);
            acc.x += lo.x; acc.y += lo.y; acc.z += hi.x; acc.w += hi.y;
        }
        row = nrow;
    }
#pragma unroll
    for (int m = 8; m <= 32; m <<= 1) {
        acc.x += __shfl_xor(acc.x, m);
        acc.y += __shfl_xor(acc.y, m);
        acc.z += __shfl_xor(acc.z, m);
        acc.w += __shfl_xor(acc.w, m);
    }
    if (sub == 0) {
        int f = slice * 32 + fl * 4;
        float sc = dinv[node];
        float4 b = *(const float4*)&bias[f];
        HF r;
        r.h[0] = __floats2half2_rn(fmaxf(sc * acc.x + b.x, 0.f),
                                   fmaxf(sc * acc.y + b.y, 0.f));
        r.h[1] = __floats2half2_rn(fmaxf(sc * acc.z + b.z, 0.f),
                                   fmaxf(sc * acc.w + b.w, 0.f));
        *(float2*)&out[(size_t)node * HID + f] = r.f;   // h1 row-major
    }
}

// ---------------- layer-2 aggregate: g2s [8][n][16] f16 -> zs [4][n][32] f16 ----
// wave per (node, agg-slice sa); 16 edges x 4 lanes x 8B per iteration.
__global__ __launch_bounds__(256) void k_agg2(
        const int* __restrict__ rowptr, const int* __restrict__ eidx,
        const __half* __restrict__ g2s, const float* __restrict__ dinv,
        const float* __restrict__ bias, __half* __restrict__ zs, int n) {
    const int sa   = blockIdx.x & 7;
    const int node = (blockIdx.x >> 3) * 4 + (threadIdx.x >> 6);
    const int lane = threadIdx.x & 63;
    const int sub  = lane >> 2;       // edge slot 0..15
    const int fl   = lane & 3;        // feats fl*4 .. fl*4+3 within 16-wide slice
    if (node >= n) return;
    const int j0   = rowptr[node];
    const int end  = rowptr[node + 1];
    const int last = max(end - 1, 0);
    const __half* base = g2s + (size_t)sa * n * 16;

    union HF { float2 f; __half2 h[2]; };
    float4 acc = make_float4(0.f, 0.f, 0.f, 0.f);
    {
        HF u; u.f = *(const float2*)&base[(size_t)node * 16 + fl * 4];
        if (sub == 0) {
            float2 lo = __half22float2(u.h[0]), hi = __half22float2(u.h[1]);
            acc = make_float4(lo.x, lo.y, hi.x, hi.y);
        }
    }
    int row = eidx[min(j0 + sub, last)];
    for (int j = j0; j < end; j += 16) {
        int nrow = eidx[min(j + 16 + sub, last)];
        HF u; u.f = *(const float2*)&base[(size_t)row * 16 + fl * 4];
        if (j + sub < end) {
            float2 lo = __half22float2(u.h[0]), hi = __half22float2(u.h[1]);
            acc.x += lo.x; acc.y += lo.y; acc.z += hi.x; acc.w += hi.y;
        }
        row = nrow;
    }
#pragma unroll
    for (int m = 4; m <= 32; m <<= 1) {
        acc.x += __shfl_xor(acc.x, m);
        acc.y += __shfl_xor(acc.y, m);
        acc.z += __shfl_xor(acc.z, m);
        acc.w += __shfl_xor(acc.w, m);
    }
    if (sub == 0) {
        int f = sa * 16 + fl * 4;                 // global z-feature
        float sc = dinv[node];
        float4 b = *(const float4*)&bias[f];
        HF r;
        r.h[0] = __floats2half2_rn(sc * acc.x + b.x, sc * acc.y + b.y);
        r.h[1] = __floats2half2_rn(sc * acc.z + b.z, sc * acc.w + b.w);
        int zslice = f >> 5;
        *(float2*)&zs[((size_t)zslice * n + node) * 32 + (f & 31)] = r.f;
    }
}

// ---------------- decode (sliced): psum[slice][e] = dot over 32 feats ----------
// zs [4][n][32] f16; wave: 8 edges x 8 lanes x 8B; slice = bx & 3.
__global__ __launch_bounds__(256) void k_decode(
        const int* __restrict__ pos, const int* __restrict__ neg,
        const __half* __restrict__ zs, float* __restrict__ psum, int E, int n) {
    const int slice = blockIdx.x & 3;
    const int wave  = threadIdx.x >> 6;
    const int lane  = threadIdx.x & 63;
    const int sub   = lane >> 3;
    const int fl    = lane & 7;
    int e = (blockIdx.x >> 2) * 32 + wave * 8 + sub;
    if (e >= 2 * E) return;
    int a, b;
    if (e < E) { a = pos[e];     b = pos[E + e]; }
    else       { a = neg[e - E]; b = neg[e];     }   // neg row1 at E + (e-E) = e
    const __half* base = zs + (size_t)slice * n * 32;
    union HF { float2 f; __half2 h[2]; };
    HF ua, ub;
    ua.f = *(const float2*)&base[(size_t)a * 32 + fl * 4];
    ub.f = *(const float2*)&base[(size_t)b * 32 + fl * 4];
    float2 a0 = __half22float2(ua.h[0]), a1 = __half22float2(ua.h[1]);
    float2 b0 = __half22float2(ub.h[0]), b1 = __half22float2(ub.h[1]);
    float p = a0.x * b0.x + a0.y * b0.y + a1.x * b1.x + a1.y * b1.y;
    p += __shfl_xor(p, 1);
    p += __shfl_xor(p, 2);
    p += __shfl_xor(p, 4);
    if (fl == 0) psum[(size_t)slice * 2 * E + e] = p;
}

// ---------------- final sum over 4 slices ----------------
__global__ void k_dsum(const float* __restrict__ psum, float* __restrict__ out, int n2e) {
    int e = blockIdx.x * blockDim.x + threadIdx.x;
    if (e < n2e)
        out[e] = (psum[e] + psum[(size_t)n2e + e]) +
                 (psum[2 * (size_t)n2e + e] + psum[3 * (size_t)n2e + e]);
}

extern "C" void kernel_launch(void* const* d_in, const int* in_sizes, int n_in,
                              void* d_out, int out_size, void* d_ws, size_t ws_size,
                              hipStream_t stream) {
    const float* x   = (const float*)d_in[0];
    const int*   tei = (const int*)d_in[1];
    const int*   pos = (const int*)d_in[2];
    const int*   neg = (const int*)d_in[3];
    const float* W1  = (const float*)d_in[4];
    const float* b1  = (const float*)d_in[5];
    const float* W2  = (const float*)d_in[6];
    const float* b2  = (const float*)d_in[7];
    float* out = (float*)d_out;

    const int N = in_sizes[0] / NFEAT;    // 50000
    const int E = in_sizes[1] / 2;        // 800000

    char* ws = (char*)d_ws;
    size_t off = 0;
    __half* g1s = (__half*)(ws + off);                 // [8][N][32] f16 (25.6MB)
    __half* g2s = (__half*)(ws + off);                 // [8][N][16] f16 (g1 dead)
    __half* zs  = (__half*)(ws + off + (size_t)N * OUTF * 2);   // [4][N][32] f16
    off += (size_t)N * HID * 2;
    __half* h1h  = (__half*)(ws + off);                // [N][256] f16 (25.6MB)
    float*  psum = (float*)(ws + off);                 // [4][2E] f32 (h1 dead after gemm2)
    off += (size_t)N * HID * 2;
    float*  dinv = (float*)(ws + off);  off += (size_t)N * 4;
    int* rowptr = (int*)(ws + off);     off += (size_t)(N + 1) * 4;
    int* cursor = (int*)(ws + off);     off += (size_t)N * 4;
    int* eidx   = (int*)(ws + off);     off += (size_t)E * 4;
    __half* W1t = (__half*)(ws + off);  off += (size_t)NFEAT * HID * 2;
    __half* W2t = (__half*)(ws + off);  off += (size_t)HID * OUTF * 2;

    // 0) weight transpose+convert
    { dim3 g(NFEAT / 32, HID / 32);  k_wt<<<g, 256, 0, stream>>>(W1, W1t, NFEAT, HID); }
    { dim3 g(HID / 32, OUTF / 32);   k_wt<<<g, 256, 0, stream>>>(W2, W2t, HID, OUTF); }

    // 1) degree -> scan -> CSR fill (shared by both layers)
    k_init_deg<<<(N + 255) / 256, 256, 0, stream>>>(dinv, N);
    k_count_deg<<<(E + 255) / 256, 256, 0, stream>>>(tei, dinv, E);
    k_scan<<<1, SCAN_T, 0, stream>>>(dinv, rowptr, cursor, N);
    k_fill<<<(E + 255) / 256, 256, 0, stream>>>(tei, cursor, eidx, E);

    // 2) layer 1: g1s = (f16, slice-major) dinv*(x@W1); h1 = relu(dinv*(agg+self)+b1)
    {
        dim3 grid((N + 127) / 128, HID / 128);
        k_gemm_mfma<4, true, 5><<<grid, 256, 0, stream>>>(x, W1t, dinv, g1s, N, NFEAT, HID);
        int nblk = 8 * ((N + 3) / 4);
        k_agg1<<<nblk, 256, 0, stream>>>(rowptr, eidx, g1s, dinv, b1, h1h, N);
    }

    // 3) layer 2: g2s = (f16, slice-major) dinv*(h1@W2); zs = dinv*(agg+self)+b2
    {
        dim3 grid((N + 63) / 64, OUTF / 128);
        k_gemm_mfma<2, false, 4><<<grid, 256, 0, stream>>>(h1h, W2t, dinv, g2s, N, HID, OUTF);
        int nblk = 8 * ((N + 3) / 4);
        k_agg2<<<nblk, 256, 0, stream>>>(rowptr, eidx, g2s, dinv, b2, zs, N);
    }

    // 4) decode: sliced partial dots + final sum
    {
        int nblk = 4 * ((2 * E + 31) / 32);
        k_decode<<<nblk, 256, 0, stream>>>(pos, neg, zs, psum, E, N);
        k_dsum<<<(2 * E + 255) / 256, 256, 0, stream>>>(psum, out, 2 * E);
    }
}

// Round 8
// 550.303 us; speedup vs baseline: 1.1796x; 1.1796x over previous
//
#include <hip/hip_runtime.h>
#include <hip/hip_fp16.h>

// GCN link-prediction forward. CSR aggregation with XCD-sliced, slice-major
// gather tables (per-XCD L2-resident); one-lane-per-task gathers (full 64B
// slice rows in registers); fp16 storage; fp16 MFMA GEMMs; sliced decode.
// Inputs: x[N,256] f32, train_edges[2,E] i32, pos[2,E] i32, neg[2,E] i32,
//         W1[256,256], b1[256], W2[256,128], b2[128]  (all f32)
// Output: logits[2E] f32.

#define NFEAT 256
#define HID   256
#define OUTF  128
#define SCAN_T 1024

typedef _Float16 f16x8 __attribute__((ext_vector_type(8)));
typedef float    f32x4 __attribute__((ext_vector_type(4)));

// ---------------- degree ----------------
__global__ void k_init_deg(float* __restrict__ deg, int n) {
    int i = blockIdx.x * blockDim.x + threadIdx.x;
    if (i < n) deg[i] = 1.0f;   // self-loop
}

__global__ void k_count_deg(const int* __restrict__ ei, float* __restrict__ deg, int E) {
    int e = blockIdx.x * blockDim.x + threadIdx.x;
    if (e < E) atomicAdd(&deg[ei[E + e]], 1.0f);   // dst row
}

// ---------------- scan: rowptr/cursor from deg, dinv in place ----------------
__global__ __launch_bounds__(SCAN_T) void k_scan(
        float* __restrict__ deg_dinv, int* __restrict__ rowptr,
        int* __restrict__ cursor, int n) {
    __shared__ int swsum[16];
    __shared__ int s_total;
    __shared__ int s_chunk;
    const int t    = threadIdx.x;
    const int wave = t >> 6;
    const int lane = t & 63;
    if (t == 0) s_total = 0;

    for (int base = 0; base < n; base += SCAN_T) {
        int i = base + t;
        float dg = 1.0f;
        int v = 0;
        if (i < n) { dg = deg_dinv[i]; v = (int)dg - 1; }  // edge count (no self)
        int sc = v;
#pragma unroll
        for (int off = 1; off < 64; off <<= 1) {
            int y = __shfl_up(sc, off);
            if (lane >= off) sc += y;
        }
        if (lane == 63) swsum[wave] = sc;
        __syncthreads();
        if (t < 16) {
            int w = swsum[t];
            int scw = w;
#pragma unroll
            for (int off = 1; off < 16; off <<= 1) {
                int y = __shfl_up(scw, off);
                if (t >= off) scw += y;
            }
            swsum[t] = scw - w;
            if (t == 15) s_chunk = scw;
        }
        __syncthreads();
        int rp = s_total + swsum[wave] + (sc - v);
        if (i < n) {
            rowptr[i] = rp;
            cursor[i] = rp;
            deg_dinv[i] = rsqrtf(dg);
        }
        __syncthreads();
        if (t == 0) s_total += s_chunk;
        __syncthreads();
    }
    if (t == 0) rowptr[n] = s_total;
}

// ---------------- fill CSR adjacency (src ids grouped by dst) ----------------
__global__ void k_fill(const int* __restrict__ ei, int* __restrict__ cursor,
                       int* __restrict__ eidx, int E) {
    int e = blockIdx.x * blockDim.x + threadIdx.x;
    if (e < E) {
        int s = ei[e];
        int d = ei[E + e];
        int p = atomicAdd(&cursor[d], 1);
        eidx[p] = s;
    }
}

// ---------------- W transpose+convert: Wt[m][k] = (half)W[k][m] ----------------
__global__ __launch_bounds__(256) void k_wt(const float* __restrict__ W,
                                            __half* __restrict__ Wt, int K, int M) {
    __shared__ float tile[32][33];
    int k0 = blockIdx.x * 32, m0 = blockIdx.y * 32;
    int tx = threadIdx.x & 31, ty = threadIdx.x >> 5;  // ty 0..7
#pragma unroll
    for (int r = 0; r < 4; ++r)
        tile[ty + r * 8][tx] = W[(size_t)(k0 + ty + r * 8) * M + m0 + tx];
    __syncthreads();
#pragma unroll
    for (int r = 0; r < 4; ++r)
        Wt[(size_t)(m0 + ty + r * 8) * K + k0 + tx] = __float2half(tile[tx][ty + r * 8]);
}

// ---------------- MFMA GEMM: out = (half)(dinv[r] * A @ Wt^T) ----------------
// Block: 256 threads = 4 waves (2x2). Block tile (2*MT*16) x 128, wave (MT*16) x 64.
// A: [n][K] (f32 if AF32 else f16). Wt: [M][K] f16. K % 32 == 0.
// Output is SLICE-MAJOR: out[(col>>SWL)][row][col & (SW-1)], SW = 1<<SWL feats/slice.
template <int MT, bool AF32, int SWL>
__global__ __launch_bounds__(256) void k_gemm_mfma(
        const void* __restrict__ Aptr, const __half* __restrict__ Wt,
        const float* __restrict__ dinv, __half* __restrict__ outp,
        int n, int K, int M) {
    constexpr int BM = 2 * MT * 16;
    __shared__ __half As[BM][40];      // [row][k], +8 pad: 2-way banks (free)
    __shared__ __half Bs[128][40];     // [col][k]
    __shared__ __half Cs[4][16][72];   // per-wave C repack (16B-aligned rows)

    const int t    = threadIdx.x;
    const int wave = t >> 6;
    const int lane = t & 63;
    const int row0 = blockIdx.x * BM;
    const int col0 = blockIdx.y * 128;
    const int wm = wave >> 1, wn = wave & 1;
    const int lr = lane & 15;          // fragment m/n index
    const int kq = lane >> 4;          // k-quad: k = kq*8 + j

    f32x4 acc[MT][4];
#pragma unroll
    for (int i = 0; i < MT; ++i)
#pragma unroll
        for (int j = 0; j < 4; ++j) acc[i][j] = (f32x4){0.f, 0.f, 0.f, 0.f};

    for (int k0 = 0; k0 < K; k0 += 32) {
        // ---- stage A tile: BM rows x 32 k ----
        if (AF32) {
            const float* A = (const float*)Aptr;
#pragma unroll
            for (int it = 0; it < BM * 8 / 256; ++it) {
                int q = t + it * 256;
                int r = q >> 3, c4 = q & 7;       // c4: which 4-float chunk
                int gr = min(row0 + r, n - 1);
                float4 v = *(const float4*)&A[(size_t)gr * K + k0 + c4 * 4];
                __half2* dst = (__half2*)&As[r][c4 * 4];
                dst[0] = __floats2half2_rn(v.x, v.y);
                dst[1] = __floats2half2_rn(v.z, v.w);
            }
        } else {
            const __half* A = (const __half*)Aptr;
#pragma unroll
            for (int it = 0; it < BM * 4 / 256; ++it) {
                int q = t + it * 256;
                int r = q >> 2, c8 = q & 3;       // c8: which 8-half chunk
                int gr = min(row0 + r, n - 1);
                *(float4*)&As[r][c8 * 8] = *(const float4*)&A[(size_t)gr * K + k0 + c8 * 8];
            }
        }
        // ---- stage B tile: 128 cols x 32 k from Wt ----
#pragma unroll
        for (int it = 0; it < 2; ++it) {
            int q = t + it * 256;
            int r = q >> 2, c8 = q & 3;
            *(float4*)&Bs[r][c8 * 8] = *(const float4*)&Wt[(size_t)(col0 + r) * K + k0 + c8 * 8];
        }
        __syncthreads();

        f16x8 b[4];
#pragma unroll
        for (int j = 0; j < 4; ++j)
            b[j] = *(const f16x8*)&Bs[wn * 64 + j * 16 + lr][kq * 8];
#pragma unroll
        for (int i = 0; i < MT; ++i) {
            f16x8 a = *(const f16x8*)&As[wm * MT * 16 + i * 16 + lr][kq * 8];
#pragma unroll
            for (int j = 0; j < 4; ++j)
                acc[i][j] = __builtin_amdgcn_mfma_f32_16x16x32_f16(a, b[j], acc[i][j], 0, 0, 0);
        }
        __syncthreads();
    }

    // ---- epilogue: scale by dinv, f16 convert, repack via LDS, slice-major stores ----
    constexpr int SW = 1 << SWL;
#pragma unroll
    for (int i = 0; i < MT; ++i) {
        int gr0 = row0 + wm * MT * 16 + i * 16;
        float dv[4];
#pragma unroll
        for (int r = 0; r < 4; ++r)
            dv[r] = dinv[min(gr0 + kq * 4 + r, n - 1)];
        __syncthreads();   // protect Cs reuse across i iterations
#pragma unroll
        for (int j = 0; j < 4; ++j)
#pragma unroll
            for (int r = 0; r < 4; ++r)
                Cs[wave][kq * 4 + r][j * 16 + lr] = __float2half(acc[i][j][r] * dv[r]);
        __syncthreads();
        int r1 = lane >> 3, c1 = (lane & 7) * 8;
#pragma unroll
        for (int h = 0; h < 2; ++h) {
            int grow = gr0 + r1 + h * 8;
            if (grow < n) {
                int col = col0 + wn * 64 + c1;    // multiple of 8; 8 halves stay in-slice
                size_t oidx = ((size_t)(col >> SWL) * n + grow) * SW + (col & (SW - 1));
                *(float4*)&outp[oidx] = *(const float4*)&Cs[wave][r1 + h * 8][c1];
            }
        }
    }
}

// ---------------- layer-1 aggregate: one lane per (node, slice-of-32) ----------
// g1s [8][n][32] f16; h1 row-major [n][256] f16. slice = bx & 7 (XCD-pinned).
__global__ __launch_bounds__(256) void k_agg1(
        const int* __restrict__ rowptr, const int* __restrict__ eidx,
        const __half* __restrict__ g1s, const float* __restrict__ dinv,
        const float* __restrict__ bias, __half* __restrict__ out, int n) {
    const int slice = blockIdx.x & 7;
    const int node  = (blockIdx.x >> 3) * 256 + threadIdx.x;
    if (node >= n) return;
    const __half* base = g1s + (size_t)slice * n * 32;

    union U { float4 f; __half2 h[4]; };
    float acc[32];
    {   // self row
        const float4* r = (const float4*)&base[(size_t)node * 32];
#pragma unroll
        for (int q = 0; q < 4; ++q) {
            U u; u.f = r[q];
#pragma unroll
            for (int k = 0; k < 4; ++k) {
                float2 v = __half22float2(u.h[k]);
                acc[q * 8 + k * 2]     = v.x;
                acc[q * 8 + k * 2 + 1] = v.y;
            }
        }
    }
    const int end = rowptr[node + 1];
    for (int j = rowptr[node]; j < end; ++j) {
        int s = eidx[j];
        const float4* r = (const float4*)&base[(size_t)s * 32];
        U u0, u1, u2, u3;
        u0.f = r[0]; u1.f = r[1]; u2.f = r[2]; u3.f = r[3];
#pragma unroll
        for (int k = 0; k < 4; ++k) {
            float2 v0 = __half22float2(u0.h[k]);
            float2 v1 = __half22float2(u1.h[k]);
            float2 v2 = __half22float2(u2.h[k]);
            float2 v3 = __half22float2(u3.h[k]);
            acc[k * 2]          += v0.x;  acc[k * 2 + 1]      += v0.y;
            acc[8 + k * 2]      += v1.x;  acc[8 + k * 2 + 1]  += v1.y;
            acc[16 + k * 2]     += v2.x;  acc[16 + k * 2 + 1] += v2.y;
            acc[24 + k * 2]     += v3.x;  acc[24 + k * 2 + 1] += v3.y;
        }
    }
    const float sc = dinv[node];
    const int f0 = slice * 32;
#pragma unroll
    for (int q = 0; q < 4; ++q) {
        U r;
#pragma unroll
        for (int k = 0; k < 4; ++k) {
            float2 bb = *(const float2*)&bias[f0 + q * 8 + k * 2];
            r.h[k] = __floats2half2_rn(
                fmaxf(sc * acc[q * 8 + k * 2]     + bb.x, 0.f),
                fmaxf(sc * acc[q * 8 + k * 2 + 1] + bb.y, 0.f));
        }
        ((float4*)&out[(size_t)node * HID + f0])[q] = r.f;
    }
}

// ---------------- layer-2 aggregate: one lane per (node, slice-of-32) ----------
// g2s [4][n][32] f16 -> zs [4][n][32] f16 (same slice). slice = bx & 3.
__global__ __launch_bounds__(256) void k_agg2(
        const int* __restrict__ rowptr, const int* __restrict__ eidx,
        const __half* __restrict__ g2s, const float* __restrict__ dinv,
        const float* __restrict__ bias, __half* __restrict__ zs, int n) {
    const int slice = blockIdx.x & 3;
    const int node  = (blockIdx.x >> 2) * 256 + threadIdx.x;
    if (node >= n) return;
    const __half* base = g2s + (size_t)slice * n * 32;

    union U { float4 f; __half2 h[4]; };
    float acc[32];
    {   // self row
        const float4* r = (const float4*)&base[(size_t)node * 32];
#pragma unroll
        for (int q = 0; q < 4; ++q) {
            U u; u.f = r[q];
#pragma unroll
            for (int k = 0; k < 4; ++k) {
                float2 v = __half22float2(u.h[k]);
                acc[q * 8 + k * 2]     = v.x;
                acc[q * 8 + k * 2 + 1] = v.y;
            }
        }
    }
    const int end = rowptr[node + 1];
    for (int j = rowptr[node]; j < end; ++j) {
        int s = eidx[j];
        const float4* r = (const float4*)&base[(size_t)s * 32];
        U u0, u1, u2, u3;
        u0.f = r[0]; u1.f = r[1]; u2.f = r[2]; u3.f = r[3];
#pragma unroll
        for (int k = 0; k < 4; ++k) {
            float2 v0 = __half22float2(u0.h[k]);
            float2 v1 = __half22float2(u1.h[k]);
            float2 v2 = __half22float2(u2.h[k]);
            float2 v3 = __half22float2(u3.h[k]);
            acc[k * 2]          += v0.x;  acc[k * 2 + 1]      += v0.y;
            acc[8 + k * 2]      += v1.x;  acc[8 + k * 2 + 1]  += v1.y;
            acc[16 + k * 2]     += v2.x;  acc[16 + k * 2 + 1] += v2.y;
            acc[24 + k * 2]     += v3.x;  acc[24 + k * 2 + 1] += v3.y;
        }
    }
    const float sc = dinv[node];
    const int f0 = slice * 32;
#pragma unroll
    for (int q = 0; q < 4; ++q) {
        U r;
#pragma unroll
        for (int k = 0; k < 4; ++k) {
            float2 bb = *(const float2*)&bias[f0 + q * 8 + k * 2];
            r.h[k] = __floats2half2_rn(sc * acc[q * 8 + k * 2]     + bb.x,
                                       sc * acc[q * 8 + k * 2 + 1] + bb.y);
        }
        ((float4*)&zs[((size_t)slice * n + node) * 32])[q] = r.f;
    }
}

// ---------------- decode (sliced): one lane per (edge, slice-of-32) ----------
// zs [4][n][32] f16; psum[slice][e]. slice = bx & 3; e coalesced within wave.
__global__ __launch_bounds__(256) void k_decode(
        const int* __restrict__ pos, const int* __restrict__ neg,
        const __half* __restrict__ zs, float* __restrict__ psum, int E, int n) {
    const int slice = blockIdx.x & 3;
    int e = (blockIdx.x >> 2) * 256 + threadIdx.x;
    if (e >= 2 * E) return;
    int a, b;
    if (e < E) { a = pos[e];     b = pos[E + e]; }
    else       { a = neg[e - E]; b = neg[e];     }   // neg row1 at E + (e-E) = e
    const __half* base = zs + (size_t)slice * n * 32;
    const float4* ra = (const float4*)&base[(size_t)a * 32];
    const float4* rb = (const float4*)&base[(size_t)b * 32];
    union U { float4 f; __half2 h[4]; };
    float p = 0.f;
#pragma unroll
    for (int q = 0; q < 4; ++q) {
        U ua, ub;
        ua.f = ra[q]; ub.f = rb[q];
#pragma unroll
        for (int k = 0; k < 4; ++k) {
            float2 va = __half22float2(ua.h[k]);
            float2 vb = __half22float2(ub.h[k]);
            p = fmaf(va.x, vb.x, p);
            p = fmaf(va.y, vb.y, p);
        }
    }
    psum[(size_t)slice * 2 * E + e] = p;
}

// ---------------- final sum over 4 slices ----------------
__global__ void k_dsum(const float* __restrict__ psum, float* __restrict__ out, int n2e) {
    int e = blockIdx.x * blockDim.x + threadIdx.x;
    if (e < n2e)
        out[e] = (psum[e] + psum[(size_t)n2e + e]) +
                 (psum[2 * (size_t)n2e + e] + psum[3 * (size_t)n2e + e]);
}

extern "C" void kernel_launch(void* const* d_in, const int* in_sizes, int n_in,
                              void* d_out, int out_size, void* d_ws, size_t ws_size,
                              hipStream_t stream) {
    const float* x   = (const float*)d_in[0];
    const int*   tei = (const int*)d_in[1];
    const int*   pos = (const int*)d_in[2];
    const int*   neg = (const int*)d_in[3];
    const float* W1  = (const float*)d_in[4];
    const float* b1  = (const float*)d_in[5];
    const float* W2  = (const float*)d_in[6];
    const float* b2  = (const float*)d_in[7];
    float* out = (float*)d_out;

    const int N = in_sizes[0] / NFEAT;    // 50000
    const int E = in_sizes[1] / 2;        // 800000

    char* ws = (char*)d_ws;
    size_t off = 0;
    __half* g1s = (__half*)(ws + off);                 // [8][N][32] f16 (25.6MB)
    __half* g2s = (__half*)(ws + off);                 // [4][N][32] f16 (g1 dead)
    __half* zs  = (__half*)(ws + off + (size_t)N * OUTF * 2);   // [4][N][32] f16
    off += (size_t)N * HID * 2;
    __half* h1h  = (__half*)(ws + off);                // [N][256] f16 (25.6MB)
    float*  psum = (float*)(ws + off);                 // [4][2E] f32 (h1 dead after gemm2)
    off += (size_t)N * HID * 2;
    float*  dinv = (float*)(ws + off);  off += (size_t)N * 4;
    int* rowptr = (int*)(ws + off);     off += (size_t)(N + 1) * 4;
    int* cursor = (int*)(ws + off);     off += (size_t)N * 4;
    int* eidx   = (int*)(ws + off);     off += (size_t)E * 4;
    __half* W1t = (__half*)(ws + off);  off += (size_t)NFEAT * HID * 2;
    __half* W2t = (__half*)(ws + off);  off += (size_t)HID * OUTF * 2;

    // 0) weight transpose+convert
    { dim3 g(NFEAT / 32, HID / 32);  k_wt<<<g, 256, 0, stream>>>(W1, W1t, NFEAT, HID); }
    { dim3 g(HID / 32, OUTF / 32);   k_wt<<<g, 256, 0, stream>>>(W2, W2t, HID, OUTF); }

    // 1) degree -> scan -> CSR fill (shared by both layers)
    k_init_deg<<<(N + 255) / 256, 256, 0, stream>>>(dinv, N);
    k_count_deg<<<(E + 255) / 256, 256, 0, stream>>>(tei, dinv, E);
    k_scan<<<1, SCAN_T, 0, stream>>>(dinv, rowptr, cursor, N);
    k_fill<<<(E + 255) / 256, 256, 0, stream>>>(tei, cursor, eidx, E);

    // 2) layer 1: g1s = (f16, [8][N][32]) dinv*(x@W1); h1 = relu(dinv*(agg+self)+b1)
    {
        dim3 grid((N + 127) / 128, HID / 128);
        k_gemm_mfma<4, true, 5><<<grid, 256, 0, stream>>>(x, W1t, dinv, g1s, N, NFEAT, HID);
        int nblk = 8 * ((N + 255) / 256);
        k_agg1<<<nblk, 256, 0, stream>>>(rowptr, eidx, g1s, dinv, b1, h1h, N);
    }

    // 3) layer 2: g2s = (f16, [4][N][32]) dinv*(h1@W2); zs = dinv*(agg+self)+b2
    {
        dim3 grid((N + 63) / 64, OUTF / 128);
        k_gemm_mfma<2, false, 5><<<grid, 256, 0, stream>>>(h1h, W2t, dinv, g2s, N, HID, OUTF);
        int nblk = 4 * ((N + 255) / 256);
        k_agg2<<<nblk, 256, 0, stream>>>(rowptr, eidx, g2s, dinv, b2, zs, N);
    }

    // 4) decode: sliced partial dots + final sum
    {
        int nblk = 4 * ((2 * E + 255) / 256);
        k_decode<<<nblk, 256, 0, stream>>>(pos, neg, zs, psum, E, N);
        k_dsum<<<(2 * E + 255) / 256, 256, 0, stream>>>(psum, out, 2 * E);
    }
}

// Round 9
// 474.579 us; speedup vs baseline: 1.3678x; 1.1596x over previous
//
#include <hip/hip_runtime.h>
#include <hip/hip_fp16.h>

// GCN link-prediction forward. CSR aggregation, row-major fp16 gather tables,
// transaction-optimal converged gathers (multiple edges per load instruction);
// fp16 MFMA GEMMs. Random-gather work is L2-transaction-bound (~4-6 cyc per
// 64B transaction per CU); decode shape is at that roofline.
// Inputs: x[N,256] f32, train_edges[2,E] i32, pos[2,E] i32, neg[2,E] i32,
//         W1[256,256], b1[256], W2[256,128], b2[128]  (all f32)
// Output: logits[2E] f32.

#define NFEAT 256
#define HID   256
#define OUTF  128
#define SCAN_T 1024

typedef _Float16 f16x8 __attribute__((ext_vector_type(8)));
typedef float    f32x4 __attribute__((ext_vector_type(4)));

// ---------------- degree ----------------
__global__ void k_init_deg(float* __restrict__ deg, int n) {
    int i = blockIdx.x * blockDim.x + threadIdx.x;
    if (i < n) deg[i] = 1.0f;   // self-loop
}

__global__ void k_count_deg(const int* __restrict__ ei, float* __restrict__ deg, int E) {
    int e = blockIdx.x * blockDim.x + threadIdx.x;
    if (e < E) atomicAdd(&deg[ei[E + e]], 1.0f);   // dst row
}

// ---------------- scan: rowptr/cursor from deg, dinv in place ----------------
__global__ __launch_bounds__(SCAN_T) void k_scan(
        float* __restrict__ deg_dinv, int* __restrict__ rowptr,
        int* __restrict__ cursor, int n) {
    __shared__ int swsum[16];
    __shared__ int s_total;
    __shared__ int s_chunk;
    const int t    = threadIdx.x;
    const int wave = t >> 6;
    const int lane = t & 63;
    if (t == 0) s_total = 0;

    for (int base = 0; base < n; base += SCAN_T) {
        int i = base + t;
        float dg = 1.0f;
        int v = 0;
        if (i < n) { dg = deg_dinv[i]; v = (int)dg - 1; }  // edge count (no self)
        int sc = v;
#pragma unroll
        for (int off = 1; off < 64; off <<= 1) {
            int y = __shfl_up(sc, off);
            if (lane >= off) sc += y;
        }
        if (lane == 63) swsum[wave] = sc;
        __syncthreads();
        if (t < 16) {
            int w = swsum[t];
            int scw = w;
#pragma unroll
            for (int off = 1; off < 16; off <<= 1) {
                int y = __shfl_up(scw, off);
                if (t >= off) scw += y;
            }
            swsum[t] = scw - w;
            if (t == 15) s_chunk = scw;
        }
        __syncthreads();
        int rp = s_total + swsum[wave] + (sc - v);
        if (i < n) {
            rowptr[i] = rp;
            cursor[i] = rp;
            deg_dinv[i] = rsqrtf(dg);
        }
        __syncthreads();
        if (t == 0) s_total += s_chunk;
        __syncthreads();
    }
    if (t == 0) rowptr[n] = s_total;
}

// ---------------- fill CSR adjacency (src ids grouped by dst) ----------------
__global__ void k_fill(const int* __restrict__ ei, int* __restrict__ cursor,
                       int* __restrict__ eidx, int E) {
    int e = blockIdx.x * blockDim.x + threadIdx.x;
    if (e < E) {
        int s = ei[e];
        int d = ei[E + e];
        int p = atomicAdd(&cursor[d], 1);
        eidx[p] = s;
    }
}

// ---------------- W transpose+convert: Wt[m][k] = (half)W[k][m] ----------------
__global__ __launch_bounds__(256) void k_wt(const float* __restrict__ W,
                                            __half* __restrict__ Wt, int K, int M) {
    __shared__ float tile[32][33];
    int k0 = blockIdx.x * 32, m0 = blockIdx.y * 32;
    int tx = threadIdx.x & 31, ty = threadIdx.x >> 5;  // ty 0..7
#pragma unroll
    for (int r = 0; r < 4; ++r)
        tile[ty + r * 8][tx] = W[(size_t)(k0 + ty + r * 8) * M + m0 + tx];
    __syncthreads();
#pragma unroll
    for (int r = 0; r < 4; ++r)
        Wt[(size_t)(m0 + ty + r * 8) * K + k0 + tx] = __float2half(tile[tx][ty + r * 8]);
}

// ---------------- MFMA GEMM: out = (half)(dinv[r] * A @ Wt^T) ----------------
// Block: 256 threads = 4 waves (2x2). Block tile (2*MT*16) x 128, wave (MT*16) x 64.
// A: [n][K] (f32 if AF32 else f16). Wt: [M][K] f16. K % 32 == 0.
// SWL=8 for M=256 / SWL=7 for M=128 give plain row-major output.
template <int MT, bool AF32, int SWL>
__global__ __launch_bounds__(256) void k_gemm_mfma(
        const void* __restrict__ Aptr, const __half* __restrict__ Wt,
        const float* __restrict__ dinv, __half* __restrict__ outp,
        int n, int K, int M) {
    constexpr int BM = 2 * MT * 16;
    __shared__ __half As[BM][40];      // [row][k], +8 pad: 2-way banks (free)
    __shared__ __half Bs[128][40];     // [col][k]
    __shared__ __half Cs[4][16][72];   // per-wave C repack (16B-aligned rows)

    const int t    = threadIdx.x;
    const int wave = t >> 6;
    const int lane = t & 63;
    const int row0 = blockIdx.x * BM;
    const int col0 = blockIdx.y * 128;
    const int wm = wave >> 1, wn = wave & 1;
    const int lr = lane & 15;          // fragment m/n index
    const int kq = lane >> 4;          // k-quad: k = kq*8 + j

    f32x4 acc[MT][4];
#pragma unroll
    for (int i = 0; i < MT; ++i)
#pragma unroll
        for (int j = 0; j < 4; ++j) acc[i][j] = (f32x4){0.f, 0.f, 0.f, 0.f};

    for (int k0 = 0; k0 < K; k0 += 32) {
        // ---- stage A tile: BM rows x 32 k ----
        if (AF32) {
            const float* A = (const float*)Aptr;
#pragma unroll
            for (int it = 0; it < BM * 8 / 256; ++it) {
                int q = t + it * 256;
                int r = q >> 3, c4 = q & 7;       // c4: which 4-float chunk
                int gr = min(row0 + r, n - 1);
                float4 v = *(const float4*)&A[(size_t)gr * K + k0 + c4 * 4];
                __half2* dst = (__half2*)&As[r][c4 * 4];
                dst[0] = __floats2half2_rn(v.x, v.y);
                dst[1] = __floats2half2_rn(v.z, v.w);
            }
        } else {
            const __half* A = (const __half*)Aptr;
#pragma unroll
            for (int it = 0; it < BM * 4 / 256; ++it) {
                int q = t + it * 256;
                int r = q >> 2, c8 = q & 3;       // c8: which 8-half chunk
                int gr = min(row0 + r, n - 1);
                *(float4*)&As[r][c8 * 8] = *(const float4*)&A[(size_t)gr * K + k0 + c8 * 8];
            }
        }
        // ---- stage B tile: 128 cols x 32 k from Wt ----
#pragma unroll
        for (int it = 0; it < 2; ++it) {
            int q = t + it * 256;
            int r = q >> 2, c8 = q & 3;
            *(float4*)&Bs[r][c8 * 8] = *(const float4*)&Wt[(size_t)(col0 + r) * K + k0 + c8 * 8];
        }
        __syncthreads();

        f16x8 b[4];
#pragma unroll
        for (int j = 0; j < 4; ++j)
            b[j] = *(const f16x8*)&Bs[wn * 64 + j * 16 + lr][kq * 8];
#pragma unroll
        for (int i = 0; i < MT; ++i) {
            f16x8 a = *(const f16x8*)&As[wm * MT * 16 + i * 16 + lr][kq * 8];
#pragma unroll
            for (int j = 0; j < 4; ++j)
                acc[i][j] = __builtin_amdgcn_mfma_f32_16x16x32_f16(a, b[j], acc[i][j], 0, 0, 0);
        }
        __syncthreads();
    }

    // ---- epilogue: scale by dinv, f16 convert, repack via LDS, 16-B stores ----
    constexpr int SW = 1 << SWL;
#pragma unroll
    for (int i = 0; i < MT; ++i) {
        int gr0 = row0 + wm * MT * 16 + i * 16;
        float dv[4];
#pragma unroll
        for (int r = 0; r < 4; ++r)
            dv[r] = dinv[min(gr0 + kq * 4 + r, n - 1)];
        __syncthreads();   // protect Cs reuse across i iterations
#pragma unroll
        for (int j = 0; j < 4; ++j)
#pragma unroll
            for (int r = 0; r < 4; ++r)
                Cs[wave][kq * 4 + r][j * 16 + lr] = __float2half(acc[i][j][r] * dv[r]);
        __syncthreads();
        int r1 = lane >> 3, c1 = (lane & 7) * 8;
#pragma unroll
        for (int h = 0; h < 2; ++h) {
            int grow = gr0 + r1 + h * 8;
            if (grow < n) {
                int col = col0 + wn * 64 + c1;    // multiple of 8
                size_t oidx = ((size_t)(col >> SWL) * n + grow) * SW + (col & (SW - 1));
                *(float4*)&outp[oidx] = *(const float4*)&Cs[wave][r1 + h * 8][c1];
            }
        }
    }
}

// ---------------- layer-1 aggregate: wave per node, 2 edges per load ----------
// g1 row-major [n][256] f16 (512B rows). lane = half(row sel) x 32 chunks x 16B.
__global__ __launch_bounds__(256) void k_agg1(
        const int* __restrict__ rowptr, const int* __restrict__ eidx,
        const __half* __restrict__ g, const float* __restrict__ dinv,
        const float* __restrict__ bias, __half* __restrict__ out, int n) {
    const int node = (int)(((size_t)blockIdx.x * blockDim.x + threadIdx.x) >> 6);
    const int lane = threadIdx.x & 63;
    const int half = lane >> 5;        // which of 2 rows this lane reads
    const int fl   = lane & 31;        // 16B chunk within row (8 halves)
    if (node >= n) return;
    const int j0  = rowptr[node];
    const int end = rowptr[node + 1];
    const int last = end - 1;          // only used when end > j0

    union U { float4 f; __half2 h[4]; };
    float acc[8] = {0.f, 0.f, 0.f, 0.f, 0.f, 0.f, 0.f, 0.f};
    {   // self row: half 0 only (avoid double count)
        if (half == 0) {
            U u; u.f = *(const float4*)&g[(size_t)node * HID + fl * 8];
#pragma unroll
            for (int k = 0; k < 4; ++k) {
                float2 v = __half22float2(u.h[k]);
                acc[k * 2] += v.x; acc[k * 2 + 1] += v.y;
            }
        }
    }
    if (j0 < end) {
        int s0 = eidx[min(j0 + half, last)];
        int s1 = eidx[min(j0 + 2 + half, last)];
        for (int j = j0; j < end; j += 4) {
            int p0 = eidx[min(j + 4 + half, last)];   // prefetch next iter's indices
            int p1 = eidx[min(j + 6 + half, last)];
            U u0, u1;
            u0.f = *(const float4*)&g[(size_t)s0 * HID + fl * 8];
            u1.f = *(const float4*)&g[(size_t)s1 * HID + fl * 8];
            if (j + half < end) {
#pragma unroll
                for (int k = 0; k < 4; ++k) {
                    float2 v = __half22float2(u0.h[k]);
                    acc[k * 2] += v.x; acc[k * 2 + 1] += v.y;
                }
            }
            if (j + 2 + half < end) {
#pragma unroll
                for (int k = 0; k < 4; ++k) {
                    float2 v = __half22float2(u1.h[k]);
                    acc[k * 2] += v.x; acc[k * 2 + 1] += v.y;
                }
            }
            s0 = p0; s1 = p1;
        }
    }
    // reduce across the two halves
#pragma unroll
    for (int k = 0; k < 8; ++k) acc[k] += __shfl_xor(acc[k], 32);
    if (half == 0) {
        const float sc = dinv[node];
        const int f0 = fl * 8;
        U r;
#pragma unroll
        for (int k = 0; k < 4; ++k) {
            float2 bb = *(const float2*)&bias[f0 + k * 2];
            r.h[k] = __floats2half2_rn(fmaxf(sc * acc[k * 2]     + bb.x, 0.f),
                                       fmaxf(sc * acc[k * 2 + 1] + bb.y, 0.f));
        }
        *(float4*)&out[(size_t)node * HID + f0] = r.f;
    }
}

// ---------------- layer-2 aggregate: wave per node, 4 edges per load ----------
// g2 row-major [n][128] f16 (256B rows). lane = q(row sel 0..3) x 16 chunks x 16B.
__global__ __launch_bounds__(256) void k_agg2(
        const int* __restrict__ rowptr, const int* __restrict__ eidx,
        const __half* __restrict__ g, const float* __restrict__ dinv,
        const float* __restrict__ bias, __half* __restrict__ out, int n) {
    const int node = (int)(((size_t)blockIdx.x * blockDim.x + threadIdx.x) >> 6);
    const int lane = threadIdx.x & 63;
    const int q    = lane >> 4;        // which of 4 rows this lane reads
    const int fl   = lane & 15;        // 16B chunk within row
    if (node >= n) return;
    const int j0  = rowptr[node];
    const int end = rowptr[node + 1];
    const int last = end - 1;

    union U { float4 f; __half2 h[4]; };
    float acc[8] = {0.f, 0.f, 0.f, 0.f, 0.f, 0.f, 0.f, 0.f};
    if (q == 0) {   // self row
        U u; u.f = *(const float4*)&g[(size_t)node * OUTF + fl * 8];
#pragma unroll
        for (int k = 0; k < 4; ++k) {
            float2 v = __half22float2(u.h[k]);
            acc[k * 2] += v.x; acc[k * 2 + 1] += v.y;
        }
    }
    if (j0 < end) {
        int s0 = eidx[min(j0 + q, last)];
        for (int j = j0; j < end; j += 4) {
            int p0 = eidx[min(j + 4 + q, last)];
            U u0; u0.f = *(const float4*)&g[(size_t)s0 * OUTF + fl * 8];
            if (j + q < end) {
#pragma unroll
                for (int k = 0; k < 4; ++k) {
                    float2 v = __half22float2(u0.h[k]);
                    acc[k * 2] += v.x; acc[k * 2 + 1] += v.y;
                }
            }
            s0 = p0;
        }
    }
#pragma unroll
    for (int k = 0; k < 8; ++k) {
        acc[k] += __shfl_xor(acc[k], 16);
        acc[k] += __shfl_xor(acc[k], 32);
    }
    if (q == 0) {
        const float sc = dinv[node];
        const int f0 = fl * 8;
        U r;
#pragma unroll
        for (int k = 0; k < 4; ++k) {
            float2 bb = *(const float2*)&bias[f0 + k * 2];
            r.h[k] = __floats2half2_rn(sc * acc[k * 2]     + bb.x,
                                       sc * acc[k * 2 + 1] + bb.y);
        }
        *(float4*)&out[(size_t)node * OUTF + f0] = r.f;
    }
}

// ---------------- decode: logits[e] = dot(z[a], z[b]) over 128 dims (fp16 z) -----
// 16 lanes per edge; each lane one 16-B load per operand. At txn roofline.
__global__ void k_decode(const int* __restrict__ pos, const int* __restrict__ neg,
                         const __half* __restrict__ z, float* __restrict__ out, int E) {
    size_t gid = (size_t)blockIdx.x * blockDim.x + threadIdx.x;
    int e  = (int)(gid >> 4);
    int sl = (int)(threadIdx.x & 15);
    if (e >= 2 * E) return;
    int a, b;
    if (e < E) { a = pos[e];     b = pos[E + e]; }
    else       { a = neg[e - E]; b = neg[e];     }   // neg row1 at E + (e-E) = e
    union HF4 { float4 f; __half2 h[4]; };
    HF4 ua, ub;
    ua.f = ((const float4*)(z + (size_t)a * OUTF))[sl];
    ub.f = ((const float4*)(z + (size_t)b * OUTF))[sl];
    float p = 0.f;
#pragma unroll
    for (int k = 0; k < 4; ++k) {
        float2 fa = __half22float2(ua.h[k]);
        float2 fb = __half22float2(ub.h[k]);
        p = fmaf(fa.x, fb.x, p);
        p = fmaf(fa.y, fb.y, p);
    }
    p += __shfl_xor(p, 1);
    p += __shfl_xor(p, 2);
    p += __shfl_xor(p, 4);
    p += __shfl_xor(p, 8);
    if (sl == 0) out[e] = p;
}

extern "C" void kernel_launch(void* const* d_in, const int* in_sizes, int n_in,
                              void* d_out, int out_size, void* d_ws, size_t ws_size,
                              hipStream_t stream) {
    const float* x   = (const float*)d_in[0];
    const int*   tei = (const int*)d_in[1];
    const int*   pos = (const int*)d_in[2];
    const int*   neg = (const int*)d_in[3];
    const float* W1  = (const float*)d_in[4];
    const float* b1  = (const float*)d_in[5];
    const float* W2  = (const float*)d_in[6];
    const float* b2  = (const float*)d_in[7];
    float* out = (float*)d_out;

    const int N = in_sizes[0] / NFEAT;    // 50000
    const int E = in_sizes[1] / 2;        // 800000

    char* ws = (char*)d_ws;
    size_t off = 0;
    __half* g1h = (__half*)(ws + off);                 // [N][256] f16 (25.6MB)
    __half* g2h = (__half*)(ws + off);                 // [N][128] f16 (g1 dead)
    __half* zh  = (__half*)(ws + off + (size_t)N * OUTF * 2);   // [N][128] f16
    off += (size_t)N * HID * 2;
    __half* h1h = (__half*)(ws + off);  off += (size_t)N * HID * 2;  // [N][256] f16
    float*  dinv = (float*)(ws + off);  off += (size_t)N * 4;
    int* rowptr = (int*)(ws + off);     off += (size_t)(N + 1) * 4;
    int* cursor = (int*)(ws + off);     off += (size_t)N * 4;
    int* eidx   = (int*)(ws + off);     off += (size_t)E * 4;
    __half* W1t = (__half*)(ws + off);  off += (size_t)NFEAT * HID * 2;
    __half* W2t = (__half*)(ws + off);  off += (size_t)HID * OUTF * 2;

    // 0) weight transpose+convert
    { dim3 g(NFEAT / 32, HID / 32);  k_wt<<<g, 256, 0, stream>>>(W1, W1t, NFEAT, HID); }
    { dim3 g(HID / 32, OUTF / 32);   k_wt<<<g, 256, 0, stream>>>(W2, W2t, HID, OUTF); }

    // 1) degree -> scan -> CSR fill (shared by both layers)
    k_init_deg<<<(N + 255) / 256, 256, 0, stream>>>(dinv, N);
    k_count_deg<<<(E + 255) / 256, 256, 0, stream>>>(tei, dinv, E);
    k_scan<<<1, SCAN_T, 0, stream>>>(dinv, rowptr, cursor, N);
    k_fill<<<(E + 255) / 256, 256, 0, stream>>>(tei, cursor, eidx, E);

    // 2) layer 1: g1 = (f16) dinv*(x@W1); h1 = (f16) relu(dinv*(agg+self)+b1)
    {
        dim3 grid((N + 127) / 128, HID / 128);
        k_gemm_mfma<4, true, 8><<<grid, 256, 0, stream>>>(x, W1t, dinv, g1h, N, NFEAT, HID);
        int nblk = (int)(((size_t)N * 64 + 255) / 256);
        k_agg1<<<nblk, 256, 0, stream>>>(rowptr, eidx, g1h, dinv, b1, h1h, N);
    }

    // 3) layer 2: g2 = (f16) dinv*(h1@W2); z = (f16) dinv*(agg+self)+b2
    {
        dim3 grid((N + 63) / 64, OUTF / 128);
        k_gemm_mfma<2, false, 7><<<grid, 256, 0, stream>>>(h1h, W2t, dinv, g2h, N, HID, OUTF);
        int nblk = (int)(((size_t)N * 64 + 255) / 256);
        k_agg2<<<nblk, 256, 0, stream>>>(rowptr, eidx, g2h, dinv, b2, zh, N);
    }

    // 4) decode
    {
        size_t nth = (size_t)2 * E * 16;   // 16 lanes per edge
        k_decode<<<(int)((nth + 255) / 256), 256, 0, stream>>>(pos, neg, zh, out, E);
    }
}

// Round 10
// 429.443 us; speedup vs baseline: 1.5115x; 1.1051x over previous
//
#include <hip/hip_runtime.h>
#include <hip/hip_fp16.h>

// GCN link-prediction forward. CSR aggregation, row-major fp16 gather tables,
// transaction-optimal converged gathers; fp16 MFMA GEMMs; parallel 3-pass
// prefix scan for CSR rowptr (the single-block serial scan was a ~1-CU tax).
// Inputs: x[N,256] f32, train_edges[2,E] i32, pos[2,E] i32, neg[2,E] i32,
//         W1[256,256], b1[256], W2[256,128], b2[128]  (all f32)
// Output: logits[2E] f32.

#define NFEAT 256
#define HID   256
#define OUTF  128

typedef _Float16 f16x8 __attribute__((ext_vector_type(8)));
typedef float    f32x4 __attribute__((ext_vector_type(4)));

// ---------------- degree ----------------
__global__ void k_init_deg(float* __restrict__ deg, int n) {
    int i = blockIdx.x * blockDim.x + threadIdx.x;
    if (i < n) deg[i] = 1.0f;   // self-loop
}

__global__ void k_count_deg(const int* __restrict__ ei, float* __restrict__ deg, int E) {
    int e = blockIdx.x * blockDim.x + threadIdx.x;
    if (e < E) atomicAdd(&deg[ei[E + e]], 1.0f);   // dst row
}

// ---------------- parallel scan, pass 1: per-block exclusive scan ----------------
// 1024 threads/block; excl[i] = exclusive scan of (deg-1) within block; bsum[b] = block total.
__global__ __launch_bounds__(1024) void k_scan1(
        const float* __restrict__ deg, int* __restrict__ excl,
        int* __restrict__ bsum, int n) {
    __shared__ int swsum[16];
    const int t = threadIdx.x, wave = t >> 6, lane = t & 63;
    const int i = blockIdx.x * 1024 + t;
    int v = (i < n) ? (int)deg[i] - 1 : 0;
    int sc = v;
#pragma unroll
    for (int off = 1; off < 64; off <<= 1) {
        int y = __shfl_up(sc, off);
        if (lane >= off) sc += y;
    }
    if (lane == 63) swsum[wave] = sc;
    __syncthreads();
    if (t < 16) {
        int w = swsum[t];
        int scw = w;
#pragma unroll
        for (int off = 1; off < 16; off <<= 1) {
            int y = __shfl_up(scw, off);
            if (t >= off) scw += y;
        }
        swsum[t] = scw - w;                        // exclusive wave offset
        if (t == 15) bsum[blockIdx.x] = scw;       // block total
    }
    __syncthreads();
    if (i < n) excl[i] = swsum[wave] + (sc - v);
}

// ---------------- pass 2: scan the (<=64) block sums in one wave ----------------
__global__ void k_scan2(int* __restrict__ bsum, int nb) {
    int t = threadIdx.x;          // 64 threads
    int v = (t < nb) ? bsum[t] : 0;
    int sc = v;
#pragma unroll
    for (int off = 1; off < 64; off <<= 1) {
        int y = __shfl_up(sc, off);
        if (t >= off) sc += y;
    }
    if (t < nb) bsum[t] = sc - v;   // exclusive
    if (t == 63) bsum[nb] = sc;     // grand total
}

// ---------------- pass 3: rowptr/cursor/dinv ----------------
__global__ void k_scan3(float* __restrict__ deg_dinv, const int* __restrict__ excl,
                        const int* __restrict__ bsum, int* __restrict__ rowptr,
                        int* __restrict__ cursor, int n, int nb) {
    int i = blockIdx.x * blockDim.x + threadIdx.x;
    if (i < n) {
        int rp = excl[i] + bsum[i >> 10];
        rowptr[i] = rp;
        cursor[i] = rp;
        deg_dinv[i] = rsqrtf(deg_dinv[i]);
    } else if (i == n) {
        rowptr[n] = bsum[nb];
    }
}

// ---------------- fill CSR adjacency (src ids grouped by dst) ----------------
__global__ void k_fill(const int* __restrict__ ei, int* __restrict__ cursor,
                       int* __restrict__ eidx, int E) {
    int e = blockIdx.x * blockDim.x + threadIdx.x;
    if (e < E) {
        int s = ei[e];
        int d = ei[E + e];
        int p = atomicAdd(&cursor[d], 1);
        eidx[p] = s;
    }
}

// ---------------- W transpose+convert: Wt[m][k] = (half)W[k][m] ----------------
__global__ __launch_bounds__(256) void k_wt(const float* __restrict__ W,
                                            __half* __restrict__ Wt, int K, int M) {
    __shared__ float tile[32][33];
    int k0 = blockIdx.x * 32, m0 = blockIdx.y * 32;
    int tx = threadIdx.x & 31, ty = threadIdx.x >> 5;  // ty 0..7
#pragma unroll
    for (int r = 0; r < 4; ++r)
        tile[ty + r * 8][tx] = W[(size_t)(k0 + ty + r * 8) * M + m0 + tx];
    __syncthreads();
#pragma unroll
    for (int r = 0; r < 4; ++r)
        Wt[(size_t)(m0 + ty + r * 8) * K + k0 + tx] = __float2half(tile[tx][ty + r * 8]);
}

// ---------------- MFMA GEMM: out = (half)(dinv[r] * A @ Wt^T) ----------------
// Block: 256 threads = 4 waves (2x2). Block tile (2*MT*16) x 128, wave (MT*16) x 64.
// A: [n][K] (f32 if AF32 else f16). Wt: [M][K] f16. K % 32 == 0.
// SWL=8 for M=256 / SWL=7 for M=128 give plain row-major output.
template <int MT, bool AF32, int SWL>
__global__ __launch_bounds__(256) void k_gemm_mfma(
        const void* __restrict__ Aptr, const __half* __restrict__ Wt,
        const float* __restrict__ dinv, __half* __restrict__ outp,
        int n, int K, int M) {
    constexpr int BM = 2 * MT * 16;
    __shared__ __half As[BM][40];      // [row][k], +8 pad: 2-way banks (free)
    __shared__ __half Bs[128][40];     // [col][k]
    __shared__ __half Cs[4][16][72];   // per-wave C repack (16B-aligned rows)

    const int t    = threadIdx.x;
    const int wave = t >> 6;
    const int lane = t & 63;
    const int row0 = blockIdx.x * BM;
    const int col0 = blockIdx.y * 128;
    const int wm = wave >> 1, wn = wave & 1;
    const int lr = lane & 15;          // fragment m/n index
    const int kq = lane >> 4;          // k-quad: k = kq*8 + j

    f32x4 acc[MT][4];
#pragma unroll
    for (int i = 0; i < MT; ++i)
#pragma unroll
        for (int j = 0; j < 4; ++j) acc[i][j] = (f32x4){0.f, 0.f, 0.f, 0.f};

    for (int k0 = 0; k0 < K; k0 += 32) {
        // ---- stage A tile: BM rows x 32 k ----
        if (AF32) {
            const float* A = (const float*)Aptr;
#pragma unroll
            for (int it = 0; it < BM * 8 / 256; ++it) {
                int q = t + it * 256;
                int r = q >> 3, c4 = q & 7;       // c4: which 4-float chunk
                int gr = min(row0 + r, n - 1);
                float4 v = *(const float4*)&A[(size_t)gr * K + k0 + c4 * 4];
                __half2* dst = (__half2*)&As[r][c4 * 4];
                dst[0] = __floats2half2_rn(v.x, v.y);
                dst[1] = __floats2half2_rn(v.z, v.w);
            }
        } else {
            const __half* A = (const __half*)Aptr;
#pragma unroll
            for (int it = 0; it < BM * 4 / 256; ++it) {
                int q = t + it * 256;
                int r = q >> 2, c8 = q & 3;       // c8: which 8-half chunk
                int gr = min(row0 + r, n - 1);
                *(float4*)&As[r][c8 * 8] = *(const float4*)&A[(size_t)gr * K + k0 + c8 * 8];
            }
        }
        // ---- stage B tile: 128 cols x 32 k from Wt ----
#pragma unroll
        for (int it = 0; it < 2; ++it) {
            int q = t + it * 256;
            int r = q >> 2, c8 = q & 3;
            *(float4*)&Bs[r][c8 * 8] = *(const float4*)&Wt[(size_t)(col0 + r) * K + k0 + c8 * 8];
        }
        __syncthreads();

        f16x8 b[4];
#pragma unroll
        for (int j = 0; j < 4; ++j)
            b[j] = *(const f16x8*)&Bs[wn * 64 + j * 16 + lr][kq * 8];
#pragma unroll
        for (int i = 0; i < MT; ++i) {
            f16x8 a = *(const f16x8*)&As[wm * MT * 16 + i * 16 + lr][kq * 8];
#pragma unroll
            for (int j = 0; j < 4; ++j)
                acc[i][j] = __builtin_amdgcn_mfma_f32_16x16x32_f16(a, b[j], acc[i][j], 0, 0, 0);
        }
        __syncthreads();
    }

    // ---- epilogue: scale by dinv, f16 convert, repack via LDS, 16-B stores ----
    constexpr int SW = 1 << SWL;
#pragma unroll
    for (int i = 0; i < MT; ++i) {
        int gr0 = row0 + wm * MT * 16 + i * 16;
        float dv[4];
#pragma unroll
        for (int r = 0; r < 4; ++r)
            dv[r] = dinv[min(gr0 + kq * 4 + r, n - 1)];
        __syncthreads();   // protect Cs reuse across i iterations
#pragma unroll
        for (int j = 0; j < 4; ++j)
#pragma unroll
            for (int r = 0; r < 4; ++r)
                Cs[wave][kq * 4 + r][j * 16 + lr] = __float2half(acc[i][j][r] * dv[r]);
        __syncthreads();
        int r1 = lane >> 3, c1 = (lane & 7) * 8;
#pragma unroll
        for (int h = 0; h < 2; ++h) {
            int grow = gr0 + r1 + h * 8;
            if (grow < n) {
                int col = col0 + wn * 64 + c1;    // multiple of 8
                size_t oidx = ((size_t)(col >> SWL) * n + grow) * SW + (col & (SW - 1));
                *(float4*)&outp[oidx] = *(const float4*)&Cs[wave][r1 + h * 8][c1];
            }
        }
    }
}

// ---------------- layer-1 aggregate: wave per node, 2 edges per load ----------
// g1 row-major [n][256] f16 (512B rows). lane = half(row sel) x 32 chunks x 16B.
__global__ __launch_bounds__(256) void k_agg1(
        const int* __restrict__ rowptr, const int* __restrict__ eidx,
        const __half* __restrict__ g, const float* __restrict__ dinv,
        const float* __restrict__ bias, __half* __restrict__ out, int n) {
    const int node = (int)(((size_t)blockIdx.x * blockDim.x + threadIdx.x) >> 6);
    const int lane = threadIdx.x & 63;
    const int half = lane >> 5;        // which of 2 rows this lane reads
    const int fl   = lane & 31;        // 16B chunk within row (8 halves)
    if (node >= n) return;
    const int j0  = rowptr[node];
    const int end = rowptr[node + 1];
    const int last = end - 1;          // only used when end > j0

    union U { float4 f; __half2 h[4]; };
    float acc[8] = {0.f, 0.f, 0.f, 0.f, 0.f, 0.f, 0.f, 0.f};
    {   // self row: half 0 only (avoid double count)
        if (half == 0) {
            U u; u.f = *(const float4*)&g[(size_t)node * HID + fl * 8];
#pragma unroll
            for (int k = 0; k < 4; ++k) {
                float2 v = __half22float2(u.h[k]);
                acc[k * 2] += v.x; acc[k * 2 + 1] += v.y;
            }
        }
    }
    if (j0 < end) {
        int s0 = eidx[min(j0 + half, last)];
        int s1 = eidx[min(j0 + 2 + half, last)];
        for (int j = j0; j < end; j += 4) {
            int p0 = eidx[min(j + 4 + half, last)];   // prefetch next iter's indices
            int p1 = eidx[min(j + 6 + half, last)];
            U u0, u1;
            u0.f = *(const float4*)&g[(size_t)s0 * HID + fl * 8];
            u1.f = *(const float4*)&g[(size_t)s1 * HID + fl * 8];
            if (j + half < end) {
#pragma unroll
                for (int k = 0; k < 4; ++k) {
                    float2 v = __half22float2(u0.h[k]);
                    acc[k * 2] += v.x; acc[k * 2 + 1] += v.y;
                }
            }
            if (j + 2 + half < end) {
#pragma unroll
                for (int k = 0; k < 4; ++k) {
                    float2 v = __half22float2(u1.h[k]);
                    acc[k * 2] += v.x; acc[k * 2 + 1] += v.y;
                }
            }
            s0 = p0; s1 = p1;
        }
    }
    // reduce across the two halves
#pragma unroll
    for (int k = 0; k < 8; ++k) acc[k] += __shfl_xor(acc[k], 32);
    if (half == 0) {
        const float sc = dinv[node];
        const int f0 = fl * 8;
        U r;
#pragma unroll
        for (int k = 0; k < 4; ++k) {
            float2 bb = *(const float2*)&bias[f0 + k * 2];
            r.h[k] = __floats2half2_rn(fmaxf(sc * acc[k * 2]     + bb.x, 0.f),
                                       fmaxf(sc * acc[k * 2 + 1] + bb.y, 0.f));
        }
        *(float4*)&out[(size_t)node * HID + f0] = r.f;
    }
}

// ---------------- layer-2 aggregate: wave per node, 4 edges per load ----------
// g2 row-major [n][128] f16 (256B rows). lane = q(row sel 0..3) x 16 chunks x 16B.
__global__ __launch_bounds__(256) void k_agg2(
        const int* __restrict__ rowptr, const int* __restrict__ eidx,
        const __half* __restrict__ g, const float* __restrict__ dinv,
        const float* __restrict__ bias, __half* __restrict__ out, int n) {
    const int node = (int)(((size_t)blockIdx.x * blockDim.x + threadIdx.x) >> 6);
    const int lane = threadIdx.x & 63;
    const int q    = lane >> 4;        // which of 4 rows this lane reads
    const int fl   = lane & 15;        // 16B chunk within row
    if (node >= n) return;
    const int j0  = rowptr[node];
    const int end = rowptr[node + 1];
    const int last = end - 1;

    union U { float4 f; __half2 h[4]; };
    float acc[8] = {0.f, 0.f, 0.f, 0.f, 0.f, 0.f, 0.f, 0.f};
    if (q == 0) {   // self row
        U u; u.f = *(const float4*)&g[(size_t)node * OUTF + fl * 8];
#pragma unroll
        for (int k = 0; k < 4; ++k) {
            float2 v = __half22float2(u.h[k]);
            acc[k * 2] += v.x; acc[k * 2 + 1] += v.y;
        }
    }
    if (j0 < end) {
        int s0 = eidx[min(j0 + q, last)];
        for (int j = j0; j < end; j += 4) {
            int p0 = eidx[min(j + 4 + q, last)];
            U u0; u0.f = *(const float4*)&g[(size_t)s0 * OUTF + fl * 8];
            if (j + q < end) {
#pragma unroll
                for (int k = 0; k < 4; ++k) {
                    float2 v = __half22float2(u0.h[k]);
                    acc[k * 2] += v.x; acc[k * 2 + 1] += v.y;
                }
            }
            s0 = p0;
        }
    }
#pragma unroll
    for (int k = 0; k < 8; ++k) {
        acc[k] += __shfl_xor(acc[k], 16);
        acc[k] += __shfl_xor(acc[k], 32);
    }
    if (q == 0) {
        const float sc = dinv[node];
        const int f0 = fl * 8;
        U r;
#pragma unroll
        for (int k = 0; k < 4; ++k) {
            float2 bb = *(const float2*)&bias[f0 + k * 2];
            r.h[k] = __floats2half2_rn(sc * acc[k * 2]     + bb.x,
                                       sc * acc[k * 2 + 1] + bb.y);
        }
        *(float4*)&out[(size_t)node * OUTF + f0] = r.f;
    }
}

// ---------------- decode: logits[e] = dot(z[a], z[b]) over 128 dims (fp16 z) -----
// 16 lanes per edge; each lane one 16-B load per operand. At txn roofline.
__global__ void k_decode(const int* __restrict__ pos, const int* __restrict__ neg,
                         const __half* __restrict__ z, float* __restrict__ out, int E) {
    size_t gid = (size_t)blockIdx.x * blockDim.x + threadIdx.x;
    int e  = (int)(gid >> 4);
    int sl = (int)(threadIdx.x & 15);
    if (e >= 2 * E) return;
    int a, b;
    if (e < E) { a = pos[e];     b = pos[E + e]; }
    else       { a = neg[e - E]; b = neg[e];     }   // neg row1 at E + (e-E) = e
    union HF4 { float4 f; __half2 h[4]; };
    HF4 ua, ub;
    ua.f = ((const float4*)(z + (size_t)a * OUTF))[sl];
    ub.f = ((const float4*)(z + (size_t)b * OUTF))[sl];
    float p = 0.f;
#pragma unroll
    for (int k = 0; k < 4; ++k) {
        float2 fa = __half22float2(ua.h[k]);
        float2 fb = __half22float2(ub.h[k]);
        p = fmaf(fa.x, fb.x, p);
        p = fmaf(fa.y, fb.y, p);
    }
    p += __shfl_xor(p, 1);
    p += __shfl_xor(p, 2);
    p += __shfl_xor(p, 4);
    p += __shfl_xor(p, 8);
    if (sl == 0) out[e] = p;
}

extern "C" void kernel_launch(void* const* d_in, const int* in_sizes, int n_in,
                              void* d_out, int out_size, void* d_ws, size_t ws_size,
                              hipStream_t stream) {
    const float* x   = (const float*)d_in[0];
    const int*   tei = (const int*)d_in[1];
    const int*   pos = (const int*)d_in[2];
    const int*   neg = (const int*)d_in[3];
    const float* W1  = (const float*)d_in[4];
    const float* b1  = (const float*)d_in[5];
    const float* W2  = (const float*)d_in[6];
    const float* b2  = (const float*)d_in[7];
    float* out = (float*)d_out;

    const int N = in_sizes[0] / NFEAT;    // 50000
    const int E = in_sizes[1] / 2;        // 800000
    const int NB = (N + 1023) / 1024;     // scan blocks (49)

    char* ws = (char*)d_ws;
    size_t off = 0;
    __half* g1h = (__half*)(ws + off);                 // [N][256] f16 (25.6MB)
    __half* g2h = (__half*)(ws + off);                 // [N][128] f16 (g1 dead)
    __half* zh  = (__half*)(ws + off + (size_t)N * OUTF * 2);   // [N][128] f16
    off += (size_t)N * HID * 2;
    __half* h1h = (__half*)(ws + off);  off += (size_t)N * HID * 2;  // [N][256] f16
    float*  dinv = (float*)(ws + off);  off += (size_t)N * 4;
    int* rowptr = (int*)(ws + off);     off += (size_t)(N + 1) * 4;
    int* cursor = (int*)(ws + off);     off += (size_t)N * 4;
    int* eidx   = (int*)(ws + off);     off += (size_t)E * 4;
    __half* W1t = (__half*)(ws + off);  off += (size_t)NFEAT * HID * 2;
    __half* W2t = (__half*)(ws + off);  off += (size_t)HID * OUTF * 2;
    int* excl   = (int*)(ws + off);     off += (size_t)N * 4;
    int* bsum   = (int*)(ws + off);     off += (size_t)(NB + 1) * 4;

    // 0) weight transpose+convert
    { dim3 g(NFEAT / 32, HID / 32);  k_wt<<<g, 256, 0, stream>>>(W1, W1t, NFEAT, HID); }
    { dim3 g(HID / 32, OUTF / 32);   k_wt<<<g, 256, 0, stream>>>(W2, W2t, HID, OUTF); }

    // 1) degree -> parallel scan -> CSR fill (shared by both layers)
    k_init_deg<<<(N + 255) / 256, 256, 0, stream>>>(dinv, N);
    k_count_deg<<<(E + 255) / 256, 256, 0, stream>>>(tei, dinv, E);
    k_scan1<<<NB, 1024, 0, stream>>>(dinv, excl, bsum, N);
    k_scan2<<<1, 64, 0, stream>>>(bsum, NB);
    k_scan3<<<(N + 256) / 256, 256, 0, stream>>>(dinv, excl, bsum, rowptr, cursor, N, NB);
    k_fill<<<(E + 255) / 256, 256, 0, stream>>>(tei, cursor, eidx, E);

    // 2) layer 1: g1 = (f16) dinv*(x@W1); h1 = (f16) relu(dinv*(agg+self)+b1)
    {
        dim3 grid((N + 127) / 128, HID / 128);
        k_gemm_mfma<4, true, 8><<<grid, 256, 0, stream>>>(x, W1t, dinv, g1h, N, NFEAT, HID);
        int nblk = (int)(((size_t)N * 64 + 255) / 256);
        k_agg1<<<nblk, 256, 0, stream>>>(rowptr, eidx, g1h, dinv, b1, h1h, N);
    }

    // 3) layer 2: g2 = (f16) dinv*(h1@W2); z = (f16) dinv*(agg+self)+b2
    {
        dim3 grid((N + 63) / 64, OUTF / 128);
        k_gemm_mfma<2, false, 7><<<grid, 256, 0, stream>>>(h1h, W2t, dinv, g2h, N, HID, OUTF);
        int nblk = (int)(((size_t)N * 64 + 255) / 256);
        k_agg2<<<nblk, 256, 0, stream>>>(rowptr, eidx, g2h, dinv, b2, zh, N);
    }

    // 4) decode
    {
        size_t nth = (size_t)2 * E * 16;   // 16 lanes per edge
        k_decode<<<(int)((nth + 255) / 256), 256, 0, stream>>>(pos, neg, zh, out, E);
    }
}

// Round 11
// 406.799 us; speedup vs baseline: 1.5957x; 1.0557x over previous
//
#include <hip/hip_runtime.h>
#include <hip/hip_fp16.h>

// GCN link-prediction forward. CSR aggregation, row-major fp16 gather tables
// for the aggregates; XCD-sliced L2-resident z for decode (zs[4][N][32], slice
// = blockIdx&3) with dot2-based 0.5-instr/edge/slice shape; fp16 MFMA GEMMs;
// parallel 3-pass prefix scan for CSR rowptr.
// Inputs: x[N,256] f32, train_edges[2,E] i32, pos[2,E] i32, neg[2,E] i32,
//         W1[256,256], b1[256], W2[256,128], b2[128]  (all f32)
// Output: logits[2E] f32.

#define NFEAT 256
#define HID   256
#define OUTF  128

typedef _Float16 f16x8 __attribute__((ext_vector_type(8)));
typedef _Float16 f16x2 __attribute__((ext_vector_type(2)));
typedef float    f32x4 __attribute__((ext_vector_type(4)));

// ---------------- degree ----------------
__global__ void k_init_deg(float* __restrict__ deg, int n) {
    int i = blockIdx.x * blockDim.x + threadIdx.x;
    if (i < n) deg[i] = 1.0f;   // self-loop
}

__global__ void k_count_deg(const int* __restrict__ ei, float* __restrict__ deg, int E) {
    int e = blockIdx.x * blockDim.x + threadIdx.x;
    if (e < E) atomicAdd(&deg[ei[E + e]], 1.0f);   // dst row
}

// ---------------- parallel scan, pass 1: per-block exclusive scan ----------------
__global__ __launch_bounds__(1024) void k_scan1(
        const float* __restrict__ deg, int* __restrict__ excl,
        int* __restrict__ bsum, int n) {
    __shared__ int swsum[16];
    const int t = threadIdx.x, wave = t >> 6, lane = t & 63;
    const int i = blockIdx.x * 1024 + t;
    int v = (i < n) ? (int)deg[i] - 1 : 0;
    int sc = v;
#pragma unroll
    for (int off = 1; off < 64; off <<= 1) {
        int y = __shfl_up(sc, off);
        if (lane >= off) sc += y;
    }
    if (lane == 63) swsum[wave] = sc;
    __syncthreads();
    if (t < 16) {
        int w = swsum[t];
        int scw = w;
#pragma unroll
        for (int off = 1; off < 16; off <<= 1) {
            int y = __shfl_up(scw, off);
            if (t >= off) scw += y;
        }
        swsum[t] = scw - w;
        if (t == 15) bsum[blockIdx.x] = scw;
    }
    __syncthreads();
    if (i < n) excl[i] = swsum[wave] + (sc - v);
}

// ---------------- pass 2: scan the (<=64) block sums in one wave ----------------
__global__ void k_scan2(int* __restrict__ bsum, int nb) {
    int t = threadIdx.x;          // 64 threads
    int v = (t < nb) ? bsum[t] : 0;
    int sc = v;
#pragma unroll
    for (int off = 1; off < 64; off <<= 1) {
        int y = __shfl_up(sc, off);
        if (t >= off) sc += y;
    }
    if (t < nb) bsum[t] = sc - v;   // exclusive
    if (t == 63) bsum[nb] = sc;     // grand total
}

// ---------------- pass 3: rowptr/cursor/dinv ----------------
__global__ void k_scan3(float* __restrict__ deg_dinv, const int* __restrict__ excl,
                        const int* __restrict__ bsum, int* __restrict__ rowptr,
                        int* __restrict__ cursor, int n, int nb) {
    int i = blockIdx.x * blockDim.x + threadIdx.x;
    if (i < n) {
        int rp = excl[i] + bsum[i >> 10];
        rowptr[i] = rp;
        cursor[i] = rp;
        deg_dinv[i] = rsqrtf(deg_dinv[i]);
    } else if (i == n) {
        rowptr[n] = bsum[nb];
    }
}

// ---------------- fill CSR adjacency (src ids grouped by dst) ----------------
__global__ void k_fill(const int* __restrict__ ei, int* __restrict__ cursor,
                       int* __restrict__ eidx, int E) {
    int e = blockIdx.x * blockDim.x + threadIdx.x;
    if (e < E) {
        int s = ei[e];
        int d = ei[E + e];
        int p = atomicAdd(&cursor[d], 1);
        eidx[p] = s;
    }
}

// ---------------- W transpose+convert: Wt[m][k] = (half)W[k][m] ----------------
__global__ __launch_bounds__(256) void k_wt(const float* __restrict__ W,
                                            __half* __restrict__ Wt, int K, int M) {
    __shared__ float tile[32][33];
    int k0 = blockIdx.x * 32, m0 = blockIdx.y * 32;
    int tx = threadIdx.x & 31, ty = threadIdx.x >> 5;  // ty 0..7
#pragma unroll
    for (int r = 0; r < 4; ++r)
        tile[ty + r * 8][tx] = W[(size_t)(k0 + ty + r * 8) * M + m0 + tx];
    __syncthreads();
#pragma unroll
    for (int r = 0; r < 4; ++r)
        Wt[(size_t)(m0 + ty + r * 8) * K + k0 + tx] = __float2half(tile[tx][ty + r * 8]);
}

// ---------------- MFMA GEMM: out = (half)(dinv[r] * A @ Wt^T) ----------------
// Block: 256 threads = 4 waves (2x2). Block tile (2*MT*16) x 128, wave (MT*16) x 64.
// A: [n][K] (f32 if AF32 else f16). Wt: [M][K] f16. K % 32 == 0.
// SWL=8 for M=256 / SWL=7 for M=128 give plain row-major output.
template <int MT, bool AF32, int SWL>
__global__ __launch_bounds__(256) void k_gemm_mfma(
        const void* __restrict__ Aptr, const __half* __restrict__ Wt,
        const float* __restrict__ dinv, __half* __restrict__ outp,
        int n, int K, int M) {
    constexpr int BM = 2 * MT * 16;
    __shared__ __half As[BM][40];      // [row][k], +8 pad: 2-way banks (free)
    __shared__ __half Bs[128][40];     // [col][k]
    __shared__ __half Cs[4][16][72];   // per-wave C repack (16B-aligned rows)

    const int t    = threadIdx.x;
    const int wave = t >> 6;
    const int lane = t & 63;
    const int row0 = blockIdx.x * BM;
    const int col0 = blockIdx.y * 128;
    const int wm = wave >> 1, wn = wave & 1;
    const int lr = lane & 15;          // fragment m/n index
    const int kq = lane >> 4;          // k-quad: k = kq*8 + j

    f32x4 acc[MT][4];
#pragma unroll
    for (int i = 0; i < MT; ++i)
#pragma unroll
        for (int j = 0; j < 4; ++j) acc[i][j] = (f32x4){0.f, 0.f, 0.f, 0.f};

    for (int k0 = 0; k0 < K; k0 += 32) {
        // ---- stage A tile: BM rows x 32 k ----
        if (AF32) {
            const float* A = (const float*)Aptr;
#pragma unroll
            for (int it = 0; it < BM * 8 / 256; ++it) {
                int q = t + it * 256;
                int r = q >> 3, c4 = q & 7;       // c4: which 4-float chunk
                int gr = min(row0 + r, n - 1);
                float4 v = *(const float4*)&A[(size_t)gr * K + k0 + c4 * 4];
                __half2* dst = (__half2*)&As[r][c4 * 4];
                dst[0] = __floats2half2_rn(v.x, v.y);
                dst[1] = __floats2half2_rn(v.z, v.w);
            }
        } else {
            const __half* A = (const __half*)Aptr;
#pragma unroll
            for (int it = 0; it < BM * 4 / 256; ++it) {
                int q = t + it * 256;
                int r = q >> 2, c8 = q & 3;       // c8: which 8-half chunk
                int gr = min(row0 + r, n - 1);
                *(float4*)&As[r][c8 * 8] = *(const float4*)&A[(size_t)gr * K + k0 + c8 * 8];
            }
        }
        // ---- stage B tile: 128 cols x 32 k from Wt ----
#pragma unroll
        for (int it = 0; it < 2; ++it) {
            int q = t + it * 256;
            int r = q >> 2, c8 = q & 3;
            *(float4*)&Bs[r][c8 * 8] = *(const float4*)&Wt[(size_t)(col0 + r) * K + k0 + c8 * 8];
        }
        __syncthreads();

        f16x8 b[4];
#pragma unroll
        for (int j = 0; j < 4; ++j)
            b[j] = *(const f16x8*)&Bs[wn * 64 + j * 16 + lr][kq * 8];
#pragma unroll
        for (int i = 0; i < MT; ++i) {
            f16x8 a = *(const f16x8*)&As[wm * MT * 16 + i * 16 + lr][kq * 8];
#pragma unroll
            for (int j = 0; j < 4; ++j)
                acc[i][j] = __builtin_amdgcn_mfma_f32_16x16x32_f16(a, b[j], acc[i][j], 0, 0, 0);
        }
        __syncthreads();
    }

    // ---- epilogue: scale by dinv, f16 convert, repack via LDS, 16-B stores ----
    constexpr int SW = 1 << SWL;
#pragma unroll
    for (int i = 0; i < MT; ++i) {
        int gr0 = row0 + wm * MT * 16 + i * 16;
        float dv[4];
#pragma unroll
        for (int r = 0; r < 4; ++r)
            dv[r] = dinv[min(gr0 + kq * 4 + r, n - 1)];
        __syncthreads();   // protect Cs reuse across i iterations
#pragma unroll
        for (int j = 0; j < 4; ++j)
#pragma unroll
            for (int r = 0; r < 4; ++r)
                Cs[wave][kq * 4 + r][j * 16 + lr] = __float2half(acc[i][j][r] * dv[r]);
        __syncthreads();
        int r1 = lane >> 3, c1 = (lane & 7) * 8;
#pragma unroll
        for (int h = 0; h < 2; ++h) {
            int grow = gr0 + r1 + h * 8;
            if (grow < n) {
                int col = col0 + wn * 64 + c1;    // multiple of 8
                size_t oidx = ((size_t)(col >> SWL) * n + grow) * SW + (col & (SW - 1));
                *(float4*)&outp[oidx] = *(const float4*)&Cs[wave][r1 + h * 8][c1];
            }
        }
    }
}

// ---------------- layer-1 aggregate: wave per node, 2 edges per load ----------
// g1 row-major [n][256] f16 (512B rows). lane = half(row sel) x 32 chunks x 16B.
__global__ __launch_bounds__(256) void k_agg1(
        const int* __restrict__ rowptr, const int* __restrict__ eidx,
        const __half* __restrict__ g, const float* __restrict__ dinv,
        const float* __restrict__ bias, __half* __restrict__ out, int n) {
    const int node = (int)(((size_t)blockIdx.x * blockDim.x + threadIdx.x) >> 6);
    const int lane = threadIdx.x & 63;
    const int half = lane >> 5;        // which of 2 rows this lane reads
    const int fl   = lane & 31;        // 16B chunk within row (8 halves)
    if (node >= n) return;
    const int j0  = rowptr[node];
    const int end = rowptr[node + 1];
    const int last = end - 1;          // only used when end > j0

    union U { float4 f; __half2 h[4]; };
    float acc[8] = {0.f, 0.f, 0.f, 0.f, 0.f, 0.f, 0.f, 0.f};
    {   // self row: half 0 only (avoid double count)
        if (half == 0) {
            U u; u.f = *(const float4*)&g[(size_t)node * HID + fl * 8];
#pragma unroll
            for (int k = 0; k < 4; ++k) {
                float2 v = __half22float2(u.h[k]);
                acc[k * 2] += v.x; acc[k * 2 + 1] += v.y;
            }
        }
    }
    if (j0 < end) {
        int s0 = eidx[min(j0 + half, last)];
        int s1 = eidx[min(j0 + 2 + half, last)];
        for (int j = j0; j < end; j += 4) {
            int p0 = eidx[min(j + 4 + half, last)];   // prefetch next iter's indices
            int p1 = eidx[min(j + 6 + half, last)];
            U u0, u1;
            u0.f = *(const float4*)&g[(size_t)s0 * HID + fl * 8];
            u1.f = *(const float4*)&g[(size_t)s1 * HID + fl * 8];
            if (j + half < end) {
#pragma unroll
                for (int k = 0; k < 4; ++k) {
                    float2 v = __half22float2(u0.h[k]);
                    acc[k * 2] += v.x; acc[k * 2 + 1] += v.y;
                }
            }
            if (j + 2 + half < end) {
#pragma unroll
                for (int k = 0; k < 4; ++k) {
                    float2 v = __half22float2(u1.h[k]);
                    acc[k * 2] += v.x; acc[k * 2 + 1] += v.y;
                }
            }
            s0 = p0; s1 = p1;
        }
    }
    // reduce across the two halves
#pragma unroll
    for (int k = 0; k < 8; ++k) acc[k] += __shfl_xor(acc[k], 32);
    if (half == 0) {
        const float sc = dinv[node];
        const int f0 = fl * 8;
        U r;
#pragma unroll
        for (int k = 0; k < 4; ++k) {
            float2 bb = *(const float2*)&bias[f0 + k * 2];
            r.h[k] = __floats2half2_rn(fmaxf(sc * acc[k * 2]     + bb.x, 0.f),
                                       fmaxf(sc * acc[k * 2 + 1] + bb.y, 0.f));
        }
        *(float4*)&out[(size_t)node * HID + f0] = r.f;
    }
}

// ---------------- layer-2 aggregate: wave per node, 4 edges per load ----------
// g2 row-major [n][128] f16 (256B rows) -> zs [4][n][32] f16 (sliced for decode).
__global__ __launch_bounds__(256) void k_agg2(
        const int* __restrict__ rowptr, const int* __restrict__ eidx,
        const __half* __restrict__ g, const float* __restrict__ dinv,
        const float* __restrict__ bias, __half* __restrict__ zs, int n) {
    const int node = (int)(((size_t)blockIdx.x * blockDim.x + threadIdx.x) >> 6);
    const int lane = threadIdx.x & 63;
    const int q    = lane >> 4;        // which of 4 rows this lane reads
    const int fl   = lane & 15;        // 16B chunk within row
    if (node >= n) return;
    const int j0  = rowptr[node];
    const int end = rowptr[node + 1];
    const int last = end - 1;

    union U { float4 f; __half2 h[4]; };
    float acc[8] = {0.f, 0.f, 0.f, 0.f, 0.f, 0.f, 0.f, 0.f};
    if (q == 0) {   // self row
        U u; u.f = *(const float4*)&g[(size_t)node * OUTF + fl * 8];
#pragma unroll
        for (int k = 0; k < 4; ++k) {
            float2 v = __half22float2(u.h[k]);
            acc[k * 2] += v.x; acc[k * 2 + 1] += v.y;
        }
    }
    if (j0 < end) {
        int s0 = eidx[min(j0 + q, last)];
        for (int j = j0; j < end; j += 4) {
            int p0 = eidx[min(j + 4 + q, last)];
            U u0; u0.f = *(const float4*)&g[(size_t)s0 * OUTF + fl * 8];
            if (j + q < end) {
#pragma unroll
                for (int k = 0; k < 4; ++k) {
                    float2 v = __half22float2(u0.h[k]);
                    acc[k * 2] += v.x; acc[k * 2 + 1] += v.y;
                }
            }
            s0 = p0;
        }
    }
#pragma unroll
    for (int k = 0; k < 8; ++k) {
        acc[k] += __shfl_xor(acc[k], 16);
        acc[k] += __shfl_xor(acc[k], 32);
    }
    if (q == 0) {
        const float sc = dinv[node];
        const int f0 = fl * 8;              // 0,8,...,120
        U r;
#pragma unroll
        for (int k = 0; k < 4; ++k) {
            float2 bb = *(const float2*)&bias[f0 + k * 2];
            r.h[k] = __floats2half2_rn(sc * acc[k * 2]     + bb.x,
                                       sc * acc[k * 2 + 1] + bb.y);
        }
        // slice-major store: slice = f0>>5, 16B chunk stays within slice
        *(float4*)&zs[((size_t)(f0 >> 5) * n + node) * 32 + (f0 & 31)] = r.f;
    }
}

// ---------------- decode (sliced): psum[slice][e], 32 edges/wave ----------------
// zs [4][n][32] f16; slice = bx & 3 (XCD-pinned, 3.2MB L2-resident).
// lane = (edge-in-wave)*2 + h; lane loads 32B of BOTH endpoint rows, 16-feat dot.
__global__ __launch_bounds__(256) void k_decode(
        const int* __restrict__ pos, const int* __restrict__ neg,
        const __half* __restrict__ zs, float* __restrict__ psum, int E, int n) {
    const int slice = blockIdx.x & 3;
    const int wv    = threadIdx.x >> 6;
    const int lane  = threadIdx.x & 63;
    const int eo    = lane >> 1;       // edge within wave (0..31)
    const int h     = lane & 1;        // which 32B half of the 64B rows
    int e = ((blockIdx.x >> 2) * 4 + wv) * 32 + eo;
    if (e >= 2 * E) return;
    int a, b;
    if (e < E) { a = pos[e];     b = pos[E + e]; }
    else       { a = neg[e - E]; b = neg[e];     }   // neg row1 at E + (e-E) = e
    const __half* ra = zs + ((size_t)slice * n + a) * 32 + h * 16;
    const __half* rb = zs + ((size_t)slice * n + b) * 32 + h * 16;
    union U { float4 f; f16x2 d[4]; };
    U a0, a1, b0, b1;
    a0.f = *(const float4*)&ra[0];
    a1.f = *(const float4*)&ra[8];
    b0.f = *(const float4*)&rb[0];
    b1.f = *(const float4*)&rb[8];
    float p = 0.f;
#if __has_builtin(__builtin_amdgcn_fdot2)
#pragma unroll
    for (int k = 0; k < 4; ++k) p = __builtin_amdgcn_fdot2(a0.d[k], b0.d[k], p, false);
#pragma unroll
    for (int k = 0; k < 4; ++k) p = __builtin_amdgcn_fdot2(a1.d[k], b1.d[k], p, false);
#else
#pragma unroll
    for (int k = 0; k < 4; ++k) {
        p += (float)a0.d[k][0] * (float)b0.d[k][0] + (float)a0.d[k][1] * (float)b0.d[k][1];
        p += (float)a1.d[k][0] * (float)b1.d[k][0] + (float)a1.d[k][1] * (float)b1.d[k][1];
    }
#endif
    p += __shfl_xor(p, 1);
    if (h == 0)
        __builtin_nontemporal_store(p, &psum[(size_t)slice * 2 * E + e]);
}

// ---------------- final sum over 4 slices ----------------
__global__ void k_dsum(const float* __restrict__ psum, float* __restrict__ out, int n2e) {
    int e = blockIdx.x * blockDim.x + threadIdx.x;
    if (e < n2e) {
        float p0 = __builtin_nontemporal_load(&psum[e]);
        float p1 = __builtin_nontemporal_load(&psum[(size_t)n2e + e]);
        float p2 = __builtin_nontemporal_load(&psum[2 * (size_t)n2e + e]);
        float p3 = __builtin_nontemporal_load(&psum[3 * (size_t)n2e + e]);
        out[e] = (p0 + p1) + (p2 + p3);
    }
}

extern "C" void kernel_launch(void* const* d_in, const int* in_sizes, int n_in,
                              void* d_out, int out_size, void* d_ws, size_t ws_size,
                              hipStream_t stream) {
    const float* x   = (const float*)d_in[0];
    const int*   tei = (const int*)d_in[1];
    const int*   pos = (const int*)d_in[2];
    const int*   neg = (const int*)d_in[3];
    const float* W1  = (const float*)d_in[4];
    const float* b1  = (const float*)d_in[5];
    const float* W2  = (const float*)d_in[6];
    const float* b2  = (const float*)d_in[7];
    float* out = (float*)d_out;

    const int N = in_sizes[0] / NFEAT;    // 50000
    const int E = in_sizes[1] / 2;        // 800000
    const int NB = (N + 1023) / 1024;     // scan blocks (49)

    char* ws = (char*)d_ws;
    size_t off = 0;
    __half* g1h = (__half*)(ws + off);                 // [N][256] f16 (25.6MB)
    __half* g2h = (__half*)(ws + off);                 // [N][128] f16 (g1 dead)
    __half* zs  = (__half*)(ws + off + (size_t)N * OUTF * 2);   // [4][N][32] f16
    off += (size_t)N * HID * 2;
    __half* h1h  = (__half*)(ws + off);                // [N][256] f16 (25.6MB)
    float*  psum = (float*)(ws + off);                 // [4][2E] f32 (h1 dead after gemm2)
    off += (size_t)N * HID * 2;
    float*  dinv = (float*)(ws + off);  off += (size_t)N * 4;
    int* rowptr = (int*)(ws + off);     off += (size_t)(N + 1) * 4;
    int* cursor = (int*)(ws + off);     off += (size_t)N * 4;
    int* eidx   = (int*)(ws + off);     off += (size_t)E * 4;
    __half* W1t = (__half*)(ws + off);  off += (size_t)NFEAT * HID * 2;
    __half* W2t = (__half*)(ws + off);  off += (size_t)HID * OUTF * 2;
    int* excl   = (int*)(ws + off);     off += (size_t)N * 4;
    int* bsum   = (int*)(ws + off);     off += (size_t)(NB + 1) * 4;

    // 0) weight transpose+convert
    { dim3 g(NFEAT / 32, HID / 32);  k_wt<<<g, 256, 0, stream>>>(W1, W1t, NFEAT, HID); }
    { dim3 g(HID / 32, OUTF / 32);   k_wt<<<g, 256, 0, stream>>>(W2, W2t, HID, OUTF); }

    // 1) degree -> parallel scan -> CSR fill (shared by both layers)
    k_init_deg<<<(N + 255) / 256, 256, 0, stream>>>(dinv, N);
    k_count_deg<<<(E + 255) / 256, 256, 0, stream>>>(tei, dinv, E);
    k_scan1<<<NB, 1024, 0, stream>>>(dinv, excl, bsum, N);
    k_scan2<<<1, 64, 0, stream>>>(bsum, NB);
    k_scan3<<<(N + 256) / 256, 256, 0, stream>>>(dinv, excl, bsum, rowptr, cursor, N, NB);
    k_fill<<<(E + 255) / 256, 256, 0, stream>>>(tei, cursor, eidx, E);

    // 2) layer 1: g1 = (f16) dinv*(x@W1); h1 = (f16) relu(dinv*(agg+self)+b1)
    {
        dim3 grid((N + 127) / 128, HID / 128);
        k_gemm_mfma<4, true, 8><<<grid, 256, 0, stream>>>(x, W1t, dinv, g1h, N, NFEAT, HID);
        int nblk = (int)(((size_t)N * 64 + 255) / 256);
        k_agg1<<<nblk, 256, 0, stream>>>(rowptr, eidx, g1h, dinv, b1, h1h, N);
    }

    // 3) layer 2: g2 = (f16) dinv*(h1@W2); zs = (f16, [4][N][32]) dinv*(agg+self)+b2
    {
        dim3 grid((N + 63) / 64, OUTF / 128);
        k_gemm_mfma<2, false, 7><<<grid, 256, 0, stream>>>(h1h, W2t, dinv, g2h, N, HID, OUTF);
        int nblk = (int)(((size_t)N * 64 + 255) / 256);
        k_agg2<<<nblk, 256, 0, stream>>>(rowptr, eidx, g2h, dinv, b2, zs, N);
    }

    // 4) decode: sliced partial dots + final sum
    {
        int nblk = 4 * ((2 * E + 127) / 128);   // 4 waves x 32 edges per block
        k_decode<<<nblk, 256, 0, stream>>>(pos, neg, zs, psum, E, N);
        k_dsum<<<(2 * E + 255) / 256, 256, 0, stream>>>(psum, out, 2 * E);
    }
}